// Round 5
// baseline (533.656 us; speedup 1.0000x reference)
//
#include <hip/hip_runtime.h>

#define NN 100000
#define NE 1600000
#define DD 128
#define NB 98        // ceil(NN/1024) for the scan
#define NGRP 8       // dst-space partitions (XCD count)
#define GBLK 128     // blocks per group for hist/fill
#define CHUNK (NE / GBLK)       // 12500 edges per block
#define CHUNK4 (CHUNK / 4)      // 3125 int4 per block
#define NPG (NN / NGRP)         // 12500 nodes per group
#define CSRCAP 1900032          // >= NE + 3*NN (deg padded to multiple of 4)

typedef __attribute__((ext_vector_type(8))) short short8;
typedef __attribute__((ext_vector_type(4))) float f32x4;
typedef __attribute__((ext_vector_type(4))) int iv4;

__device__ __forceinline__ iv4 ntld4(const int* p) {
  return __builtin_nontemporal_load((const iv4*)p);
}

__device__ __forceinline__ unsigned bf16rn(float f) {
  unsigned u = __float_as_uint(f);
  return (u + 0x7fffu + ((u >> 16) & 1u)) >> 16;  // round-to-nearest-even
}
__device__ __forceinline__ unsigned pk2(float a, float b) {
  return bf16rn(a) | (bf16rn(b) << 16);
}
__device__ __forceinline__ float lo_f(unsigned u) { return __uint_as_float(u << 16); }
__device__ __forceinline__ float hi_f(unsigned u) { return __uint_as_float(u & 0xffff0000u); }

// ---------------- preprocessing ----------------

__global__ __launch_bounds__(64) void k_detect(const unsigned int* __restrict__ w,
                                               int* __restrict__ flag) {
  int lane = threadIdx.x;
  int z = 0;
  for (int i = lane; i < 256; i += 64)
    if (w[2 * i + 1] == 0u) z++;  // high words of first 256 int64s
  for (int d = 32; d > 0; d >>= 1) z += __shfl_down(z, d);
  if (lane == 0) *flag = (z >= 250) ? 1 : 0;
}

__global__ __launch_bounds__(256) void k_convert(const void* __restrict__ ei,
                                                 const int* __restrict__ flag,
                                                 int* __restrict__ ec) {
  int i = blockIdx.x * 256 + threadIdx.x;
  if (i < 2 * NE) {
    if (*flag)
      ec[i] = (int)((const long long*)ei)[i];
    else
      ec[i] = ((const int*)ei)[i];
  }
}

// zero degree counts + prefill csr with the dummy zero-row index NN
__global__ __launch_bounds__(256) void k_init(int* __restrict__ cnt,
                                              int* __restrict__ csr) {
  int i = blockIdx.x * 256 + threadIdx.x;
  if (i < NN) cnt[i] = 0;
  if (i < CSRCAP) csr[i] = NN;
}

// dst-partitioned histogram (XCD-local atomics). ec reads are NON-TEMPORAL:
// the 25.6MB stream must not evict the cnt accumulation set from L2.
__global__ __launch_bounds__(256) void k_hist(const int* __restrict__ ec,
                                              int* __restrict__ cnt) {
  const int g = blockIdx.x & (NGRP - 1);
  const int bslot = blockIdx.x >> 3;
  const int lo = g * NPG, hi = lo + NPG;
  const int* dbase = ec + NE + (size_t)bslot * CHUNK;
  for (int v = threadIdx.x; v < CHUNK4; v += 256) {
    iv4 d = ntld4(dbase + v * 4);
    if (d.x >= lo && d.x < hi) atomicAdd(&cnt[d.x], 1);
    if (d.y >= lo && d.y < hi) atomicAdd(&cnt[d.y], 1);
    if (d.z >= lo && d.z < hi) atomicAdd(&cnt[d.z], 1);
    if (d.w >= lo && d.w < hi) atomicAdd(&cnt[d.w], 1);
  }
}

// dinv + zero the dummy T row (row NN)
__global__ __launch_bounds__(256) void k_dinv(const int* __restrict__ cnt,
                                              float* __restrict__ dinv,
                                              unsigned* __restrict__ tbuf) {
  int i = blockIdx.x * 256 + threadIdx.x;
  if (i < NN) dinv[i] = rsqrtf((float)(cnt[i] + 1));  // +1 self-loop
  if (blockIdx.x == 0 && threadIdx.x < 64) tbuf[(size_t)NN * 64 + threadIdx.x] = 0u;
}

// scans below use PADDED counts: pc = (cnt+3) & ~3  (int4-aligned segments)
__global__ __launch_bounds__(256) void k_scan1(const int* __restrict__ cnt,
                                               int* __restrict__ bsums) {
  __shared__ int sd[256];
  const int tid = threadIdx.x;
  const int base = blockIdx.x * 1024;
  int s = 0;
#pragma unroll
  for (int j = 0; j < 4; j++) {
    int i = base + tid * 4 + j;
    if (i < NN) s += (cnt[i] + 3) & ~3;
  }
  sd[tid] = s;
  __syncthreads();
  for (int d = 128; d > 0; d >>= 1) {
    if (tid < d) sd[tid] += sd[tid + d];
    __syncthreads();
  }
  if (tid == 0) bsums[blockIdx.x] = sd[0];
}

__global__ __launch_bounds__(128) void k_scan2(int* __restrict__ bsums,
                                               int* __restrict__ offs) {
  __shared__ int sd[128];
  const int tid = threadIdx.x;
  int v = (tid < NB) ? bsums[tid] : 0;
  sd[tid] = v;
  __syncthreads();
  for (int d = 1; d < 128; d <<= 1) {
    int t = (tid >= d) ? sd[tid - d] : 0;
    __syncthreads();
    sd[tid] += t;
    __syncthreads();
  }
  if (tid < NB) bsums[tid] = sd[tid] - v;  // exclusive
  if (tid == 127) offs[NN] = sd[127];      // padded total
}

__global__ __launch_bounds__(256) void k_scan3(const int* __restrict__ cnt,
                                               const int* __restrict__ bsums,
                                               int* __restrict__ offs,
                                               int* __restrict__ cursor) {
  __shared__ int sd[256];
  const int tid = threadIdx.x;
  const int base = blockIdx.x * 1024;
  int v[4];
  int s = 0;
#pragma unroll
  for (int j = 0; j < 4; j++) {
    int i = base + tid * 4 + j;
    v[j] = (i < NN) ? ((cnt[i] + 3) & ~3) : 0;
    s += v[j];
  }
  sd[tid] = s;
  __syncthreads();
  for (int d = 1; d < 256; d <<= 1) {
    int t = (tid >= d) ? sd[tid - d] : 0;
    __syncthreads();
    if (tid >= d) sd[tid] += t;
    __syncthreads();
  }
  int run = bsums[blockIdx.x] + sd[tid] - s;
#pragma unroll
  for (int j = 0; j < 4; j++) {
    int i = base + tid * 4 + j;
    if (i < NN) {
      offs[i] = run;
      cursor[i] = run;
    }
    run += v[j];
  }
}

// dst-partitioned CSR fill. ec reads NON-TEMPORAL so the per-XCD ~1MB csr
// accumulation region stays L2-resident until lines are full (R4: WRITE was
// 75MB for 7.6MB payload = partial-line eviction thrash from the read stream).
__global__ __launch_bounds__(256) void k_fill(const int* __restrict__ ec,
                                              int* __restrict__ cursor,
                                              int* __restrict__ csr) {
  const int g = blockIdx.x & (NGRP - 1);
  const int bslot = blockIdx.x >> 3;
  const int lo = g * NPG, hi = lo + NPG;
  const int* dbase = ec + NE + (size_t)bslot * CHUNK;
  const int* sbase = ec + (size_t)bslot * CHUNK;
  for (int v = threadIdx.x; v < CHUNK4; v += 256) {
    iv4 d = ntld4(dbase + v * 4);
    iv4 s = ntld4(sbase + v * 4);
    if (d.x >= lo && d.x < hi) csr[atomicAdd(&cursor[d.x], 1)] = s.x;
    if (d.y >= lo && d.y < hi) csr[atomicAdd(&cursor[d.y], 1)] = s.y;
    if (d.z >= lo && d.z < hi) csr[atomicAdd(&cursor[d.z], 1)] = s.z;
    if (d.w >= lo && d.w < hi) csr[atomicAdd(&cursor[d.w], 1)] = s.w;
  }
}

// Wt[n][k] = bf16(W[k][n]), packed 2 bf16 per uint (k pairs)
__global__ __launch_bounds__(256) void k_prepw(const float* __restrict__ W,
                                               unsigned* __restrict__ wt) {
  int id = blockIdx.x * 256 + threadIdx.x;  // 0..8191
  int n = id >> 6, kp = id & 63;
  wt[n * 64 + kp] = pk2(W[(size_t)(2 * kp) * DD + n], W[(size_t)(2 * kp + 1) * DD + n]);
}

// ---------------- MFMA GEMM:  T[r][:] = bf16( (A[r][:] @ W) * dinv[r] ) ----
// 64-row x 128-col tile, 4 waves (32 cols each), 16x16x32 bf16 MFMA.
// LDS: A-tile 16KB + Wt 32KB, both XOR-swizzled (byte ^= (row&7)<<4 per 16B seg).
template <bool F32SRC>
__global__ __launch_bounds__(256) void k_gemm(const void* __restrict__ Av,
                                              const unsigned* __restrict__ Wg,
                                              const float* __restrict__ dinv,
                                              unsigned* __restrict__ T) {
  __shared__ char lds[49408];  // 0:A(16K) 16384:Wt(32K) 49152:dinv(256B)
  const int t = threadIdx.x;
  const int row0 = blockIdx.x * 64;
  const int w = t >> 6, l = t & 63;
  const int lm = l & 15, kb = l >> 4;

  // stage A tile (64 rows x 128 bf16)
  {
    int r = t >> 2;
    int gr = row0 + r;
#pragma unroll
    for (int s4 = 0; s4 < 4; s4++) {
      int sg = (t & 3) * 4 + s4;  // 16B segment 0..15
      uint4 u;
      if (gr < NN) {
        if (F32SRC) {
          const float* ap = (const float*)Av + (size_t)gr * DD + sg * 8;
          float4 f0 = *(const float4*)ap;
          float4 f1 = *(const float4*)(ap + 4);
          u.x = pk2(f0.x, f0.y); u.y = pk2(f0.z, f0.w);
          u.z = pk2(f1.x, f1.y); u.w = pk2(f1.z, f1.w);
        } else {
          u = *(const uint4*)((const unsigned*)Av + (size_t)gr * 64 + sg * 4);
        }
      } else {
        u = make_uint4(0u, 0u, 0u, 0u);
      }
      *(uint4*)(lds + r * 256 + ((sg * 16) ^ ((r & 7) << 4))) = u;
    }
  }
  // stage Wt (128 rows x 128 bf16)
#pragma unroll
  for (int q = 0; q < 8; q++) {
    int e = t * 8 + q;  // 0..2047
    int n = e >> 4, sg = e & 15;
    uint4 u = *(const uint4*)(Wg + n * 64 + sg * 4);
    *(uint4*)(lds + 16384 + n * 256 + ((sg * 16) ^ ((n & 7) << 4))) = u;
  }
  // stage dinv
  if (t < 64) {
    int gr = row0 + t;
    *(float*)(lds + 49152 + t * 4) = (gr < NN) ? dinv[gr] : 0.f;
  }
  __syncthreads();

  f32x4 acc[4][2];
#pragma unroll
  for (int i = 0; i < 4; i++)
#pragma unroll
    for (int j = 0; j < 2; j++) acc[i][j] = (f32x4){0.f, 0.f, 0.f, 0.f};

#pragma unroll
  for (int kk = 0; kk < 4; kk++) {
    const int koff = (kk * 4 + kb) * 16;  // byte offset of this lane's 8 bf16
    short8 af[4], bf[2];
#pragma unroll
    for (int i = 0; i < 4; i++) {
      int r = i * 16 + lm;
      af[i] = *(const short8*)(lds + r * 256 + (koff ^ ((r & 7) << 4)));
    }
#pragma unroll
    for (int j = 0; j < 2; j++) {
      int n = w * 32 + j * 16 + lm;
      bf[j] = *(const short8*)(lds + 16384 + n * 256 + (koff ^ ((n & 7) << 4)));
    }
#pragma unroll
    for (int i = 0; i < 4; i++)
#pragma unroll
      for (int j = 0; j < 2; j++)
        acc[i][j] = __builtin_amdgcn_mfma_f32_16x16x32_bf16(af[i], bf[j], acc[i][j], 0, 0, 0);
  }

  // epilogue: scale by dinv[row], pack col-pairs via shfl, store uints
#pragma unroll
  for (int i = 0; i < 4; i++) {
#pragma unroll
    for (int j = 0; j < 2; j++) {
#pragma unroll
      for (int q = 0; q < 4; q++) {
        int rl = i * 16 + (l >> 4) * 4 + q;  // local row
        float s = *(const float*)(lds + 49152 + rl * 4);
        float v = acc[i][j][q] * s;
        float nb = __shfl_xor(v, 1);
        if ((l & 1) == 0) {
          int gr = row0 + rl;
          if (gr < NN) {
            int cp = w * 16 + j * 8 + (lm >> 1);
            T[(size_t)gr * 64 + cp] = pk2(v, nb);
          }
        }
      }
    }
  }
}

// ---------------- aggregation ----------------
// out[i] = relu(dinv[i] * (T[i] + sum_{e in CSR[i]} T[src_e]) + b)
// one wave per node; segments padded to x4 with dummy row NN (zeros).
// csr index loads are non-temporal (read-once; keep T rows L2-resident).
template <bool BF16OUT>
__global__ __launch_bounds__(256) void k_agg(const unsigned* __restrict__ T,
                                             const int* __restrict__ offs,
                                             const int* __restrict__ csr,
                                             const float* __restrict__ dinv,
                                             const float* __restrict__ bias,
                                             void* __restrict__ outv) {
  const int lane = threadIdx.x & 63;
  const int node = blockIdx.x * 4 + (threadIdx.x >> 6);
  if (node >= NN) return;
  unsigned su = T[(size_t)node * 64 + lane];  // self-loop term
  float accx = lo_f(su), accy = hi_f(su);
  int j = offs[node];
  const int end = offs[node + 1];
  for (; j + 16 <= end; j += 16) {
    iv4 c0 = ntld4(csr + j);
    iv4 c1 = ntld4(csr + j + 4);
    iv4 c2 = ntld4(csr + j + 8);
    iv4 c3 = ntld4(csr + j + 12);
    unsigned u0 = T[(size_t)c0.x * 64 + lane];
    unsigned u1 = T[(size_t)c0.y * 64 + lane];
    unsigned u2 = T[(size_t)c0.z * 64 + lane];
    unsigned u3 = T[(size_t)c0.w * 64 + lane];
    unsigned u4 = T[(size_t)c1.x * 64 + lane];
    unsigned u5 = T[(size_t)c1.y * 64 + lane];
    unsigned u6 = T[(size_t)c1.z * 64 + lane];
    unsigned u7 = T[(size_t)c1.w * 64 + lane];
    unsigned u8 = T[(size_t)c2.x * 64 + lane];
    unsigned u9 = T[(size_t)c2.y * 64 + lane];
    unsigned ua = T[(size_t)c2.z * 64 + lane];
    unsigned ub = T[(size_t)c2.w * 64 + lane];
    unsigned uc = T[(size_t)c3.x * 64 + lane];
    unsigned ud = T[(size_t)c3.y * 64 + lane];
    unsigned ue = T[(size_t)c3.z * 64 + lane];
    unsigned uf = T[(size_t)c3.w * 64 + lane];
    accx += (((lo_f(u0) + lo_f(u1)) + (lo_f(u2) + lo_f(u3))) +
             ((lo_f(u4) + lo_f(u5)) + (lo_f(u6) + lo_f(u7)))) +
            (((lo_f(u8) + lo_f(u9)) + (lo_f(ua) + lo_f(ub))) +
             ((lo_f(uc) + lo_f(ud)) + (lo_f(ue) + lo_f(uf))));
    accy += (((hi_f(u0) + hi_f(u1)) + (hi_f(u2) + hi_f(u3))) +
             ((hi_f(u4) + hi_f(u5)) + (hi_f(u6) + hi_f(u7)))) +
            (((hi_f(u8) + hi_f(u9)) + (hi_f(ua) + hi_f(ub))) +
             ((hi_f(uc) + hi_f(ud)) + (hi_f(ue) + hi_f(uf))));
  }
  for (; j < end; j += 4) {
    iv4 c = ntld4(csr + j);
    unsigned u0 = T[(size_t)c.x * 64 + lane];
    unsigned u1 = T[(size_t)c.y * 64 + lane];
    unsigned u2 = T[(size_t)c.z * 64 + lane];
    unsigned u3 = T[(size_t)c.w * 64 + lane];
    accx += (lo_f(u0) + lo_f(u1)) + (lo_f(u2) + lo_f(u3));
    accy += (hi_f(u0) + hi_f(u1)) + (hi_f(u2) + hi_f(u3));
  }
  float s = dinv[node];
  float2 bb = ((const float2*)bias)[lane];
  float ox = fmaxf(accx * s + bb.x, 0.f);
  float oy = fmaxf(accy * s + bb.y, 0.f);
  if (BF16OUT)
    ((unsigned*)outv)[(size_t)node * 64 + lane] = pk2(ox, oy);
  else
    ((float2*)outv)[(size_t)node * 64 + lane] = make_float2(ox, oy);
}

// ---------------- launch ----------------

extern "C" void kernel_launch(void* const* d_in, const int* in_sizes, int n_in,
                              void* d_out, int out_size, void* d_ws, size_t ws_size,
                              hipStream_t stream) {
  const float* x = (const float*)d_in[0];
  const void* ei = (const void*)d_in[1];
  const float* W1 = (const float*)d_in[2];
  const float* b1 = (const float*)d_in[3];
  const float* W2 = (const float*)d_in[4];
  const float* b2 = (const float*)d_in[5];
  const float* W3 = (const float*)d_in[6];
  const float* b3 = (const float*)d_in[7];
  float* out = (float*)d_out;

  char* p = (char*)d_ws;
  auto take = [&](size_t bytes) {
    char* r = p;
    p += (bytes + 1023) & ~(size_t)1023;
    return r;
  };
  int* flag = (int*)take(4);
  int* cnt = (int*)take((size_t)NN * 4);
  int* offs = (int*)take((size_t)(NN + 1) * 4);
  int* cursor = (int*)take((size_t)NN * 4);
  int* bsums = (int*)take((size_t)NB * 4);
  float* dinv = (float*)take((size_t)NN * 4);
  int* ec = (int*)take((size_t)2 * NE * 4);
  int* csr = (int*)take((size_t)CSRCAP * 4);
  unsigned* tbuf = (unsigned*)take((size_t)(NN + 1) * 64 * 4);  // +1 dummy zero row
  unsigned* hbuf = (unsigned*)take((size_t)NN * 64 * 4);        // bf16 hidden
  unsigned* wt1 = (unsigned*)take((size_t)DD * 64 * 4);
  unsigned* wt2 = (unsigned*)take((size_t)DD * 64 * 4);
  unsigned* wt3 = (unsigned*)take((size_t)DD * 64 * 4);

  const int nb_2e = (2 * NE + 255) / 256;
  const int nb_cap = (CSRCAP + 255) / 256;
  const int nb_n = (NN + 255) / 256;

  k_detect<<<1, 64, 0, stream>>>((const unsigned int*)ei, flag);
  k_convert<<<nb_2e, 256, 0, stream>>>(ei, flag, ec);
  k_init<<<nb_cap, 256, 0, stream>>>(cnt, csr);
  k_hist<<<NGRP * GBLK, 256, 0, stream>>>(ec, cnt);
  k_dinv<<<nb_n, 256, 0, stream>>>(cnt, dinv, tbuf);
  k_scan1<<<NB, 256, 0, stream>>>(cnt, bsums);
  k_scan2<<<1, 128, 0, stream>>>(bsums, offs);
  k_scan3<<<NB, 256, 0, stream>>>(cnt, bsums, offs, cursor);
  k_fill<<<NGRP * GBLK, 256, 0, stream>>>(ec, cursor, csr);
  k_prepw<<<32, 256, 0, stream>>>(W1, wt1);
  k_prepw<<<32, 256, 0, stream>>>(W2, wt2);
  k_prepw<<<32, 256, 0, stream>>>(W3, wt3);

  const int gb = (NN + 63) / 64;
  const int ab = (NN + 3) / 4;
  k_gemm<true><<<gb, 256, 0, stream>>>(x, wt1, dinv, tbuf);
  k_agg<true><<<ab, 256, 0, stream>>>(tbuf, offs, csr, dinv, b1, hbuf);
  k_gemm<false><<<gb, 256, 0, stream>>>(hbuf, wt2, dinv, tbuf);
  k_agg<true><<<ab, 256, 0, stream>>>(tbuf, offs, csr, dinv, b2, hbuf);
  k_gemm<false><<<gb, 256, 0, stream>>>(hbuf, wt3, dinv, tbuf);
  k_agg<false><<<ab, 256, 0, stream>>>(tbuf, offs, csr, dinv, b3, out);
}

// Round 6
// 523.976 us; speedup vs baseline: 1.0185x; 1.0185x over previous
//
#include <hip/hip_runtime.h>

#define NN 100000
#define NE 1600000
#define DD 128
#define NB 98        // ceil(NN/1024) for the scan
#define NGRP 8       // dst-space partitions (XCD count)
#define NPG (NN / NGRP)         // 12500 nodes per group
#define CSRCAP 1900032          // >= NE + 3*NN (deg padded to multiple of 4)
#define NBLK_B 1024             // bucket-phase blocks
#define EPB 1563                // edges per bucket block (1563*1024 >= NE)
#define BCAP 210000             // per-bucket capacity (exp 200K, 23 sigma)

typedef __attribute__((ext_vector_type(8))) short short8;
typedef __attribute__((ext_vector_type(4))) float f32x4;

__device__ __forceinline__ unsigned bf16rn(float f) {
  unsigned u = __float_as_uint(f);
  return (u + 0x7fffu + ((u >> 16) & 1u)) >> 16;  // round-to-nearest-even
}
__device__ __forceinline__ unsigned pk2(float a, float b) {
  return bf16rn(a) | (bf16rn(b) << 16);
}
__device__ __forceinline__ float lo_f(unsigned u) { return __uint_as_float(u << 16); }
__device__ __forceinline__ float hi_f(unsigned u) { return __uint_as_float(u & 0xffff0000u); }

// ---------------- preprocessing ----------------

// detect int64 vs int32 edge data; zero the 8 bucket cursors
__global__ __launch_bounds__(64) void k_detect(const unsigned int* __restrict__ w,
                                               int* __restrict__ flag,
                                               int* __restrict__ gcur) {
  int lane = threadIdx.x;
  if (lane < NGRP) gcur[lane] = 0;
  int z = 0;
  for (int i = lane; i < 256; i += 64)
    if (w[2 * i + 1] == 0u) z++;  // high words of first 256 int64s
  for (int d = 32; d > 0; d >>= 1) z += __shfl_down(z, d);
  if (lane == 0) *flag = (z >= 250) ? 1 : 0;
}

// Phase 1: partition edges into 8 dst-range buckets (SoA), sequential appends.
// Replaces k_convert + the thrashing full-stream scatter: each (block,bucket)
// reserves a contiguous run via ONE global atomic, then appends -> full lines.
__global__ __launch_bounds__(256) void k_bucket(const void* __restrict__ ei,
                                                const int* __restrict__ flag,
                                                int* __restrict__ bsrc,
                                                int* __restrict__ bdst,
                                                int* __restrict__ gcur) {
  __shared__ int lcnt[NGRP], lbase[NGRP], lcur[NGRP];
  const int t = threadIdx.x;
  const long long e0 = (long long)blockIdx.x * EPB;
  const int nE = (int)((NE - e0) < EPB ? (NE - e0) : EPB);
  if (t < NGRP) { lcnt[t] = 0; lcur[t] = 0; }
  __syncthreads();
  int es[7], ed[7], eb[7];
  const int isLL = *flag;
#pragma unroll
  for (int k = 0; k < 7; k++) {
    int idx = t + k * 256;
    eb[k] = -1;
    if (idx < nE) {
      long long e = e0 + idx;
      if (isLL) {
        es[k] = (int)((const long long*)ei)[e];
        ed[k] = (int)((const long long*)ei)[NE + e];
      } else {
        es[k] = ((const int*)ei)[e];
        ed[k] = ((const int*)ei)[NE + e];
      }
      eb[k] = ed[k] / NPG;
      atomicAdd(&lcnt[eb[k]], 1);
    }
  }
  __syncthreads();
  if (t < NGRP) lbase[t] = atomicAdd(&gcur[t], lcnt[t]);
  __syncthreads();
#pragma unroll
  for (int k = 0; k < 7; k++) {
    if (eb[k] >= 0) {
      int p = lbase[eb[k]] + atomicAdd(&lcur[eb[k]], 1);
      size_t o = (size_t)eb[k] * BCAP + p;
      bsrc[o] = es[k];
      bdst[o] = ed[k];
    }
  }
}

// zero degree counts + prefill csr with the dummy zero-row index NN
__global__ __launch_bounds__(256) void k_init(int* __restrict__ cnt,
                                              int* __restrict__ csr) {
  int i = blockIdx.x * 256 + threadIdx.x;
  if (i < NN) cnt[i] = 0;
  if (i < CSRCAP) csr[i] = NN;
}

// histogram from buckets: group g (XCD-affine) streams only its ~800KB dst
// bucket; cnt range + stream both fit in one XCD's 4MB L2.
__global__ __launch_bounds__(256) void k_histb(const int* __restrict__ bdst,
                                               const int* __restrict__ gcur,
                                               int* __restrict__ cnt) {
  const int g = blockIdx.x & (NGRP - 1);
  const int bslot = blockIdx.x >> 3;
  const int n = gcur[g];
  const int* dp = bdst + (size_t)g * BCAP;
  for (int i = bslot * 256 + threadIdx.x; i < n; i += 128 * 256)
    atomicAdd(&cnt[dp[i]], 1);
}

// dinv + zero the dummy T row (row NN)
__global__ __launch_bounds__(256) void k_dinv(const int* __restrict__ cnt,
                                              float* __restrict__ dinv,
                                              unsigned* __restrict__ tbuf) {
  int i = blockIdx.x * 256 + threadIdx.x;
  if (i < NN) dinv[i] = rsqrtf((float)(cnt[i] + 1));  // +1 self-loop
  if (blockIdx.x == 0 && threadIdx.x < 64) tbuf[(size_t)NN * 64 + threadIdx.x] = 0u;
}

// scans below use PADDED counts: pc = (cnt+3) & ~3  (int4-aligned segments)
__global__ __launch_bounds__(256) void k_scan1(const int* __restrict__ cnt,
                                               int* __restrict__ bsums) {
  __shared__ int sd[256];
  const int tid = threadIdx.x;
  const int base = blockIdx.x * 1024;
  int s = 0;
#pragma unroll
  for (int j = 0; j < 4; j++) {
    int i = base + tid * 4 + j;
    if (i < NN) s += (cnt[i] + 3) & ~3;
  }
  sd[tid] = s;
  __syncthreads();
  for (int d = 128; d > 0; d >>= 1) {
    if (tid < d) sd[tid] += sd[tid + d];
    __syncthreads();
  }
  if (tid == 0) bsums[blockIdx.x] = sd[0];
}

__global__ __launch_bounds__(128) void k_scan2(int* __restrict__ bsums,
                                               int* __restrict__ offs) {
  __shared__ int sd[128];
  const int tid = threadIdx.x;
  int v = (tid < NB) ? bsums[tid] : 0;
  sd[tid] = v;
  __syncthreads();
  for (int d = 1; d < 128; d <<= 1) {
    int t = (tid >= d) ? sd[tid - d] : 0;
    __syncthreads();
    sd[tid] += t;
    __syncthreads();
  }
  if (tid < NB) bsums[tid] = sd[tid] - v;  // exclusive
  if (tid == 127) offs[NN] = sd[127];      // padded total
}

__global__ __launch_bounds__(256) void k_scan3(const int* __restrict__ cnt,
                                               const int* __restrict__ bsums,
                                               int* __restrict__ offs,
                                               int* __restrict__ cursor) {
  __shared__ int sd[256];
  const int tid = threadIdx.x;
  const int base = blockIdx.x * 1024;
  int v[4];
  int s = 0;
#pragma unroll
  for (int j = 0; j < 4; j++) {
    int i = base + tid * 4 + j;
    v[j] = (i < NN) ? ((cnt[i] + 3) & ~3) : 0;
    s += v[j];
  }
  sd[tid] = s;
  __syncthreads();
  for (int d = 1; d < 256; d <<= 1) {
    int t = (tid >= d) ? sd[tid - d] : 0;
    __syncthreads();
    if (tid >= d) sd[tid] += t;
    __syncthreads();
  }
  int run = bsums[blockIdx.x] + sd[tid] - s;
#pragma unroll
  for (int j = 0; j < 4; j++) {
    int i = base + tid * 4 + j;
    if (i < NN) {
      offs[i] = run;
      cursor[i] = run;
    }
    run += v[j];
  }
}

// Phase 2 scatter: group g streams only bucket g (~1.7MB) into its contiguous
// ~800KB csr region; stream + accumulation set fit in the XCD's 4MB L2.
__global__ __launch_bounds__(256) void k_scatter(const int* __restrict__ bsrc,
                                                 const int* __restrict__ bdst,
                                                 const int* __restrict__ gcur,
                                                 int* __restrict__ cursor,
                                                 int* __restrict__ csr) {
  const int g = blockIdx.x & (NGRP - 1);
  const int bslot = blockIdx.x >> 3;
  const int n = gcur[g];
  const int* sp = bsrc + (size_t)g * BCAP;
  const int* dp = bdst + (size_t)g * BCAP;
  for (int i = bslot * 256 + threadIdx.x; i < n; i += 128 * 256) {
    int d = dp[i];
    int pos = atomicAdd(&cursor[d], 1);
    csr[pos] = sp[i];
  }
}

// Wt[n][k] = bf16(W[k][n]) for all 3 layers in one launch (96 blocks)
__global__ __launch_bounds__(256) void k_prepw(const float* __restrict__ Wa,
                                               const float* __restrict__ Wb,
                                               const float* __restrict__ Wc,
                                               unsigned* __restrict__ wt) {
  int id = blockIdx.x * 256 + threadIdx.x;  // 0..24575
  int layer = id >> 13;                     // 8192 per layer
  int r = id & 8191;
  int n = r >> 6, kp = r & 63;
  const float* W = (layer == 0) ? Wa : (layer == 1) ? Wb : Wc;
  wt[(size_t)layer * 8192 + n * 64 + kp] =
      pk2(W[(size_t)(2 * kp) * DD + n], W[(size_t)(2 * kp + 1) * DD + n]);
}

// ---------------- MFMA GEMM:  T[r][:] = bf16( (A[r][:] @ W) * dinv[r] ) ----
template <bool F32SRC>
__global__ __launch_bounds__(256) void k_gemm(const void* __restrict__ Av,
                                              const unsigned* __restrict__ Wg,
                                              const float* __restrict__ dinv,
                                              unsigned* __restrict__ T) {
  __shared__ char lds[49408];  // 0:A(16K) 16384:Wt(32K) 49152:dinv(256B)
  const int t = threadIdx.x;
  const int row0 = blockIdx.x * 64;
  const int w = t >> 6, l = t & 63;
  const int lm = l & 15, kb = l >> 4;

  // stage A tile (64 rows x 128 bf16)
  {
    int r = t >> 2;
    int gr = row0 + r;
#pragma unroll
    for (int s4 = 0; s4 < 4; s4++) {
      int sg = (t & 3) * 4 + s4;  // 16B segment 0..15
      uint4 u;
      if (gr < NN) {
        if (F32SRC) {
          const float* ap = (const float*)Av + (size_t)gr * DD + sg * 8;
          float4 f0 = *(const float4*)ap;
          float4 f1 = *(const float4*)(ap + 4);
          u.x = pk2(f0.x, f0.y); u.y = pk2(f0.z, f0.w);
          u.z = pk2(f1.x, f1.y); u.w = pk2(f1.z, f1.w);
        } else {
          u = *(const uint4*)((const unsigned*)Av + (size_t)gr * 64 + sg * 4);
        }
      } else {
        u = make_uint4(0u, 0u, 0u, 0u);
      }
      *(uint4*)(lds + r * 256 + ((sg * 16) ^ ((r & 7) << 4))) = u;
    }
  }
  // stage Wt (128 rows x 128 bf16)
#pragma unroll
  for (int q = 0; q < 8; q++) {
    int e = t * 8 + q;  // 0..2047
    int n = e >> 4, sg = e & 15;
    uint4 u = *(const uint4*)(Wg + n * 64 + sg * 4);
    *(uint4*)(lds + 16384 + n * 256 + ((sg * 16) ^ ((n & 7) << 4))) = u;
  }
  // stage dinv
  if (t < 64) {
    int gr = row0 + t;
    *(float*)(lds + 49152 + t * 4) = (gr < NN) ? dinv[gr] : 0.f;
  }
  __syncthreads();

  f32x4 acc[4][2];
#pragma unroll
  for (int i = 0; i < 4; i++)
#pragma unroll
    for (int j = 0; j < 2; j++) acc[i][j] = (f32x4){0.f, 0.f, 0.f, 0.f};

#pragma unroll
  for (int kk = 0; kk < 4; kk++) {
    const int koff = (kk * 4 + kb) * 16;  // byte offset of this lane's 8 bf16
    short8 af[4], bf[2];
#pragma unroll
    for (int i = 0; i < 4; i++) {
      int r = i * 16 + lm;
      af[i] = *(const short8*)(lds + r * 256 + (koff ^ ((r & 7) << 4)));
    }
#pragma unroll
    for (int j = 0; j < 2; j++) {
      int n = w * 32 + j * 16 + lm;
      bf[j] = *(const short8*)(lds + 16384 + n * 256 + (koff ^ ((n & 7) << 4)));
    }
#pragma unroll
    for (int i = 0; i < 4; i++)
#pragma unroll
      for (int j = 0; j < 2; j++)
        acc[i][j] = __builtin_amdgcn_mfma_f32_16x16x32_bf16(af[i], bf[j], acc[i][j], 0, 0, 0);
  }

  // epilogue: scale by dinv[row], pack col-pairs via shfl, store uints
#pragma unroll
  for (int i = 0; i < 4; i++) {
#pragma unroll
    for (int j = 0; j < 2; j++) {
#pragma unroll
      for (int q = 0; q < 4; q++) {
        int rl = i * 16 + (l >> 4) * 4 + q;  // local row
        float s = *(const float*)(lds + 49152 + rl * 4);
        float v = acc[i][j][q] * s;
        float nb = __shfl_xor(v, 1);
        if ((l & 1) == 0) {
          int gr = row0 + rl;
          if (gr < NN) {
            int cp = w * 16 + j * 8 + (lm >> 1);
            T[(size_t)gr * 64 + cp] = pk2(v, nb);
          }
        }
      }
    }
  }
}

// ---------------- aggregation ----------------
// out[i] = relu(dinv[i] * (T[i] + sum_{e in CSR[i]} T[src_e]) + b)
template <bool BF16OUT>
__global__ __launch_bounds__(256) void k_agg(const unsigned* __restrict__ T,
                                             const int* __restrict__ offs,
                                             const int* __restrict__ csr,
                                             const float* __restrict__ dinv,
                                             const float* __restrict__ bias,
                                             void* __restrict__ outv) {
  const int lane = threadIdx.x & 63;
  const int node = blockIdx.x * 4 + (threadIdx.x >> 6);
  if (node >= NN) return;
  unsigned su = T[(size_t)node * 64 + lane];  // self-loop term
  float accx = lo_f(su), accy = hi_f(su);
  int j = offs[node];
  const int end = offs[node + 1];
  for (; j + 16 <= end; j += 16) {
    int4 c0 = *(const int4*)(csr + j);
    int4 c1 = *(const int4*)(csr + j + 4);
    int4 c2 = *(const int4*)(csr + j + 8);
    int4 c3 = *(const int4*)(csr + j + 12);
    unsigned u0 = T[(size_t)c0.x * 64 + lane];
    unsigned u1 = T[(size_t)c0.y * 64 + lane];
    unsigned u2 = T[(size_t)c0.z * 64 + lane];
    unsigned u3 = T[(size_t)c0.w * 64 + lane];
    unsigned u4 = T[(size_t)c1.x * 64 + lane];
    unsigned u5 = T[(size_t)c1.y * 64 + lane];
    unsigned u6 = T[(size_t)c1.z * 64 + lane];
    unsigned u7 = T[(size_t)c1.w * 64 + lane];
    unsigned u8 = T[(size_t)c2.x * 64 + lane];
    unsigned u9 = T[(size_t)c2.y * 64 + lane];
    unsigned ua = T[(size_t)c2.z * 64 + lane];
    unsigned ub = T[(size_t)c2.w * 64 + lane];
    unsigned uc = T[(size_t)c3.x * 64 + lane];
    unsigned ud = T[(size_t)c3.y * 64 + lane];
    unsigned ue = T[(size_t)c3.z * 64 + lane];
    unsigned uf = T[(size_t)c3.w * 64 + lane];
    accx += (((lo_f(u0) + lo_f(u1)) + (lo_f(u2) + lo_f(u3))) +
             ((lo_f(u4) + lo_f(u5)) + (lo_f(u6) + lo_f(u7)))) +
            (((lo_f(u8) + lo_f(u9)) + (lo_f(ua) + lo_f(ub))) +
             ((lo_f(uc) + lo_f(ud)) + (lo_f(ue) + lo_f(uf))));
    accy += (((hi_f(u0) + hi_f(u1)) + (hi_f(u2) + hi_f(u3))) +
             ((hi_f(u4) + hi_f(u5)) + (hi_f(u6) + hi_f(u7)))) +
            (((hi_f(u8) + hi_f(u9)) + (hi_f(ua) + hi_f(ub))) +
             ((hi_f(uc) + hi_f(ud)) + (hi_f(ue) + hi_f(uf))));
  }
  for (; j < end; j += 4) {
    int4 c = *(const int4*)(csr + j);
    unsigned u0 = T[(size_t)c.x * 64 + lane];
    unsigned u1 = T[(size_t)c.y * 64 + lane];
    unsigned u2 = T[(size_t)c.z * 64 + lane];
    unsigned u3 = T[(size_t)c.w * 64 + lane];
    accx += (lo_f(u0) + lo_f(u1)) + (lo_f(u2) + lo_f(u3));
    accy += (hi_f(u0) + hi_f(u1)) + (hi_f(u2) + hi_f(u3));
  }
  float s = dinv[node];
  float2 bb = ((const float2*)bias)[lane];
  float ox = fmaxf(accx * s + bb.x, 0.f);
  float oy = fmaxf(accy * s + bb.y, 0.f);
  if (BF16OUT)
    ((unsigned*)outv)[(size_t)node * 64 + lane] = pk2(ox, oy);
  else
    ((float2*)outv)[(size_t)node * 64 + lane] = make_float2(ox, oy);
}

// ---------------- launch ----------------

extern "C" void kernel_launch(void* const* d_in, const int* in_sizes, int n_in,
                              void* d_out, int out_size, void* d_ws, size_t ws_size,
                              hipStream_t stream) {
  const float* x = (const float*)d_in[0];
  const void* ei = (const void*)d_in[1];
  const float* W1 = (const float*)d_in[2];
  const float* b1 = (const float*)d_in[3];
  const float* W2 = (const float*)d_in[4];
  const float* b2 = (const float*)d_in[5];
  const float* W3 = (const float*)d_in[6];
  const float* b3 = (const float*)d_in[7];
  float* out = (float*)d_out;

  char* p = (char*)d_ws;
  auto take = [&](size_t bytes) {
    char* r = p;
    p += (bytes + 1023) & ~(size_t)1023;
    return r;
  };
  int* flag = (int*)take(4);
  int* gcur = (int*)take((size_t)NGRP * 4);
  int* cnt = (int*)take((size_t)NN * 4);
  int* offs = (int*)take((size_t)(NN + 1) * 4);
  int* cursor = (int*)take((size_t)NN * 4);
  int* bsums = (int*)take((size_t)NB * 4);
  float* dinv = (float*)take((size_t)NN * 4);
  int* bsrc = (int*)take((size_t)NGRP * BCAP * 4);
  int* bdst = (int*)take((size_t)NGRP * BCAP * 4);
  int* csr = (int*)take((size_t)CSRCAP * 4);
  unsigned* tbuf = (unsigned*)take((size_t)(NN + 1) * 64 * 4);  // +1 dummy zero row
  unsigned* hbuf = (unsigned*)take((size_t)NN * 64 * 4);        // bf16 hidden
  unsigned* wt = (unsigned*)take((size_t)3 * DD * 64 * 4);

  const int nb_cap = (CSRCAP + 255) / 256;
  const int nb_n = (NN + 255) / 256;

  k_detect<<<1, 64, 0, stream>>>((const unsigned int*)ei, flag, gcur);
  k_bucket<<<NBLK_B, 256, 0, stream>>>(ei, flag, bsrc, bdst, gcur);
  k_init<<<nb_cap, 256, 0, stream>>>(cnt, csr);
  k_histb<<<NBLK_B, 256, 0, stream>>>(bdst, gcur, cnt);
  k_dinv<<<nb_n, 256, 0, stream>>>(cnt, dinv, tbuf);
  k_scan1<<<NB, 256, 0, stream>>>(cnt, bsums);
  k_scan2<<<1, 128, 0, stream>>>(bsums, offs);
  k_scan3<<<NB, 256, 0, stream>>>(cnt, bsums, offs, cursor);
  k_scatter<<<NBLK_B, 256, 0, stream>>>(bsrc, bdst, gcur, cursor, csr);
  k_prepw<<<96, 256, 0, stream>>>(W1, W2, W3, wt);

  const int gb = (NN + 63) / 64;
  const int ab = (NN + 3) / 4;
  k_gemm<true><<<gb, 256, 0, stream>>>(x, wt, dinv, tbuf);
  k_agg<true><<<ab, 256, 0, stream>>>(tbuf, offs, csr, dinv, b1, hbuf);
  k_gemm<false><<<gb, 256, 0, stream>>>(hbuf, wt + 8192, dinv, tbuf);
  k_agg<true><<<ab, 256, 0, stream>>>(tbuf, offs, csr, dinv, b2, hbuf);
  k_gemm<false><<<gb, 256, 0, stream>>>(hbuf, wt + 16384, dinv, tbuf);
  k_agg<false><<<ab, 256, 0, stream>>>(tbuf, offs, csr, dinv, b3, out);
}

// Round 7
// 486.430 us; speedup vs baseline: 1.0971x; 1.0772x over previous
//
#include <hip/hip_runtime.h>

#define NN 100000
#define NE 1600000
#define DD 128
#define NB 98        // ceil(NN/1024) for the scan
#define NGRP 8       // dst-space partitions
#define NPG (NN / NGRP)         // 12500 nodes per group
#define CSRCAP 1900032          // >= padded total (mean 1.75M, huge margin)
#define NBLK_B 1024             // bucket-phase blocks
#define EPB 1563                // edges per bucket block (1563*1024 >= NE)
#define BCAP 210000             // per-bucket capacity (mean 200K, 22 sigma)
#define WJ 256                  // dst-window size (nodes)
#define NW 49                   // windows per group = ceil(12500/256)
#define NSUB (NGRP * NW)        // 392 sub-buckets
#define SCAP 4608               // edges per sub-bucket (mean 4096, 8 sigma)
#define LCAP 5632               // padded csr region per window (mean 4480, 17 sigma)

typedef __attribute__((ext_vector_type(8))) short short8;
typedef __attribute__((ext_vector_type(4))) float f32x4;

__device__ __forceinline__ unsigned bf16rn(float f) {
  unsigned u = __float_as_uint(f);
  return (u + 0x7fffu + ((u >> 16) & 1u)) >> 16;  // round-to-nearest-even
}
__device__ __forceinline__ unsigned pk2(float a, float b) {
  return bf16rn(a) | (bf16rn(b) << 16);
}
__device__ __forceinline__ float lo_f(unsigned u) { return __uint_as_float(u << 16); }
__device__ __forceinline__ float hi_f(unsigned u) { return __uint_as_float(u & 0xffff0000u); }

// ---------------- preprocessing ----------------

// zero cnt + bucket cursors + sub-bucket cursors
__global__ __launch_bounds__(256) void k_init(int* __restrict__ cnt,
                                              int* __restrict__ gcur,
                                              int* __restrict__ scur) {
  int i = blockIdx.x * 256 + threadIdx.x;
  if (i < NN) cnt[i] = 0;
  if (i < NGRP) gcur[i] = 0;
  if (i < NSUB) scur[i] = 0;
}

// Phase 1: partition edges into 8 dst-range buckets (SoA). int64-vs-int32
// detection is done per-block (cheap, L2-broadcast) -- k_detect removed.
__global__ __launch_bounds__(256) void k_bucket(const void* __restrict__ ei,
                                                int* __restrict__ bsrc,
                                                int* __restrict__ bdst,
                                                int* __restrict__ gcur) {
  __shared__ int lcnt[NGRP], lbase[NGRP], lcur[NGRP], zcnt;
  const int t = threadIdx.x;
  if (t == 0) zcnt = 0;
  if (t < NGRP) { lcnt[t] = 0; lcur[t] = 0; }
  __syncthreads();
  if (t < 64) {
    const unsigned* w = (const unsigned*)ei;
    int z = 0;
    for (int i = t; i < 256; i += 64)
      if (w[2 * i + 1] == 0u) z++;
    atomicAdd(&zcnt, z);
  }
  __syncthreads();
  const int isLL = (zcnt >= 250);
  const long long e0 = (long long)blockIdx.x * EPB;
  const int nE = (int)((NE - e0) < EPB ? (NE - e0) : EPB);
  int es[7], ed[7], eb[7];
#pragma unroll
  for (int k = 0; k < 7; k++) {
    int idx = t + k * 256;
    eb[k] = -1;
    if (idx < nE) {
      long long e = e0 + idx;
      if (isLL) {
        es[k] = (int)((const long long*)ei)[e];
        ed[k] = (int)((const long long*)ei)[NE + e];
      } else {
        es[k] = ((const int*)ei)[e];
        ed[k] = ((const int*)ei)[NE + e];
      }
      eb[k] = ed[k] / NPG;
      atomicAdd(&lcnt[eb[k]], 1);
    }
  }
  __syncthreads();
  if (t < NGRP) lbase[t] = atomicAdd(&gcur[t], lcnt[t]);
  __syncthreads();
#pragma unroll
  for (int k = 0; k < 7; k++) {
    if (eb[k] >= 0) {
      int p = lbase[eb[k]] + atomicAdd(&lcur[eb[k]], 1);
      size_t o = (size_t)eb[k] * BCAP + p;
      bsrc[o] = es[k];
      bdst[o] = ed[k];
    }
  }
}

// Phase 2: split bucket g into 49 windows of 256 dst nodes. Two-pass per
// block: LDS count -> ONE global reservation per (block,window) -> placed
// append (runs ~250 entries = full lines). Degree histogram folded in.
__global__ __launch_bounds__(256) void k_sub(const int* __restrict__ bsrc,
                                             const int* __restrict__ bdst,
                                             const int* __restrict__ gcur,
                                             int* __restrict__ cnt,
                                             int* __restrict__ ssrc,
                                             int* __restrict__ sdst,
                                             int* __restrict__ scur) {
  __shared__ int lcnt[NW], lbase[NW], lcur[NW];
  const int g = blockIdx.x & (NGRP - 1);
  const int s = blockIdx.x >> 3;  // 16 slots per group
  const int n = gcur[g];
  const int chunk = (n + 15) >> 4;
  const int e0 = s * chunk;
  const int e1 = min(e0 + chunk, n);
  const int t = threadIdx.x;
  if (t < NW) { lcnt[t] = 0; lcur[t] = 0; }
  __syncthreads();
  const int* dp = bdst + (size_t)g * BCAP;
  const int* sp = bsrc + (size_t)g * BCAP;
  for (int i = e0 + t; i < e1; i += 256) {
    int d = dp[i];
    atomicAdd(&cnt[d], 1);                      // degree histogram
    atomicAdd(&lcnt[(d - g * NPG) >> 8], 1);    // window count
  }
  __syncthreads();
  if (t < NW) lbase[t] = atomicAdd(&scur[g * NW + t], lcnt[t]);
  __syncthreads();
  for (int i = e0 + t; i < e1; i += 256) {
    int d = dp[i];
    int srcv = sp[i];
    int w = (d - g * NPG) >> 8;
    int p = lbase[w] + atomicAdd(&lcur[w], 1);
    size_t o = (size_t)(g * NW + w) * SCAP + p;
    ssrc[o] = srcv;
    sdst[o] = d;
  }
}

// dinv from degree counts
__global__ __launch_bounds__(256) void k_dinv(const int* __restrict__ cnt,
                                              float* __restrict__ dinv) {
  int i = blockIdx.x * 256 + threadIdx.x;
  if (i < NN) dinv[i] = rsqrtf((float)(cnt[i] + 1));  // +1 self-loop
}

// scans use PADDED counts: pc = (cnt+3) & ~3  (int4-aligned segments)
__global__ __launch_bounds__(256) void k_scan1(const int* __restrict__ cnt,
                                               int* __restrict__ bsums) {
  __shared__ int sd[256];
  const int tid = threadIdx.x;
  const int base = blockIdx.x * 1024;
  int s = 0;
#pragma unroll
  for (int j = 0; j < 4; j++) {
    int i = base + tid * 4 + j;
    if (i < NN) s += (cnt[i] + 3) & ~3;
  }
  sd[tid] = s;
  __syncthreads();
  for (int d = 128; d > 0; d >>= 1) {
    if (tid < d) sd[tid] += sd[tid + d];
    __syncthreads();
  }
  if (tid == 0) bsums[blockIdx.x] = sd[0];
}

__global__ __launch_bounds__(128) void k_scan2(int* __restrict__ bsums,
                                               int* __restrict__ offs) {
  __shared__ int sd[128];
  const int tid = threadIdx.x;
  int v = (tid < NB) ? bsums[tid] : 0;
  sd[tid] = v;
  __syncthreads();
  for (int d = 1; d < 128; d <<= 1) {
    int t = (tid >= d) ? sd[tid - d] : 0;
    __syncthreads();
    sd[tid] += t;
    __syncthreads();
  }
  if (tid < NB) bsums[tid] = sd[tid] - v;  // exclusive
  if (tid == 127) offs[NN] = sd[127];      // padded total
}

__global__ __launch_bounds__(256) void k_scan3(const int* __restrict__ cnt,
                                               const int* __restrict__ bsums,
                                               int* __restrict__ offs) {
  __shared__ int sd[256];
  const int tid = threadIdx.x;
  const int base = blockIdx.x * 1024;
  int v[4];
  int s = 0;
#pragma unroll
  for (int j = 0; j < 4; j++) {
    int i = base + tid * 4 + j;
    v[j] = (i < NN) ? ((cnt[i] + 3) & ~3) : 0;
    s += v[j];
  }
  sd[tid] = s;
  __syncthreads();
  for (int d = 1; d < 256; d <<= 1) {
    int t = (tid >= d) ? sd[tid - d] : 0;
    __syncthreads();
    if (tid >= d) sd[tid] += t;
    __syncthreads();
  }
  int run = bsums[blockIdx.x] + sd[tid] - s;
#pragma unroll
  for (int j = 0; j < 4; j++) {
    int i = base + tid * 4 + j;
    if (i < NN) offs[i] = run;
    run += v[j];
  }
}

// Phase 3: per-window LDS counting-scatter, then ONE sequential coalesced
// write of the whole padded csr region (incl. dummy NN slots). No scattered
// global stores -> no partial-line writeback, independent of L2 behavior.
__global__ __launch_bounds__(256) void k_csr(const int* __restrict__ ssrc,
                                             const int* __restrict__ sdst,
                                             const int* __restrict__ scur,
                                             const int* __restrict__ offs,
                                             int* __restrict__ csr) {
  __shared__ int L[LCAP];
  __shared__ int loff[WJ], lcur[WJ];
  __shared__ int sR0, sRlen, sm;
  const int b = blockIdx.x;
  const int g = b / NW, w = b % NW;
  const int n0 = g * NPG + w * WJ;
  const int wn = min(WJ, NPG - w * WJ);
  const int t = threadIdx.x;
  for (int i = t; i < LCAP; i += 256) L[i] = NN;  // dummy zero-row index
  if (t == 0) {
    sR0 = offs[n0];
    sRlen = offs[n0 + wn] - sR0;
    sm = scur[b];
  }
  __syncthreads();
  const int R0 = sR0, Rlen = sRlen, m = sm;
  for (int i = t; i < wn; i += 256) {
    loff[i] = offs[n0 + i] - R0;
    lcur[i] = 0;
  }
  __syncthreads();
  const int* sp = ssrc + (size_t)b * SCAP;
  const int* dp = sdst + (size_t)b * SCAP;
  for (int e = t; e < m; e += 256) {
    int dl = dp[e] - n0;
    int pos = loff[dl] + atomicAdd(&lcur[dl], 1);
    if (pos < LCAP) L[pos] = sp[e];
  }
  __syncthreads();
  for (int i = t * 4; i < Rlen; i += 1024)
    if (i + 3 < LCAP) *(int4*)(csr + R0 + i) = *(const int4*)&L[i];
}

// Wt[n][k] = bf16(W[k][n]) all 3 layers; also zero the dummy T row (row NN)
__global__ __launch_bounds__(256) void k_prepw(const float* __restrict__ Wa,
                                               const float* __restrict__ Wb,
                                               const float* __restrict__ Wc,
                                               unsigned* __restrict__ wt,
                                               unsigned* __restrict__ tbuf) {
  if (blockIdx.x == 0 && threadIdx.x < 64)
    tbuf[(size_t)NN * 64 + threadIdx.x] = 0u;
  int id = blockIdx.x * 256 + threadIdx.x;  // 0..24575
  int layer = id >> 13;                     // 8192 per layer
  int r = id & 8191;
  int n = r >> 6, kp = r & 63;
  const float* W = (layer == 0) ? Wa : (layer == 1) ? Wb : Wc;
  wt[(size_t)layer * 8192 + n * 64 + kp] =
      pk2(W[(size_t)(2 * kp) * DD + n], W[(size_t)(2 * kp + 1) * DD + n]);
}

// ---------------- MFMA GEMM:  T[r][:] = bf16( (A[r][:] @ W) * dinv[r] ) ----
template <bool F32SRC>
__global__ __launch_bounds__(256) void k_gemm(const void* __restrict__ Av,
                                              const unsigned* __restrict__ Wg,
                                              const float* __restrict__ dinv,
                                              unsigned* __restrict__ T) {
  __shared__ char lds[49408];  // 0:A(16K) 16384:Wt(32K) 49152:dinv(256B)
  const int t = threadIdx.x;
  const int row0 = blockIdx.x * 64;
  const int w = t >> 6, l = t & 63;
  const int lm = l & 15, kb = l >> 4;

  // stage A tile (64 rows x 128 bf16)
  {
    int r = t >> 2;
    int gr = row0 + r;
#pragma unroll
    for (int s4 = 0; s4 < 4; s4++) {
      int sg = (t & 3) * 4 + s4;  // 16B segment 0..15
      uint4 u;
      if (gr < NN) {
        if (F32SRC) {
          const float* ap = (const float*)Av + (size_t)gr * DD + sg * 8;
          float4 f0 = *(const float4*)ap;
          float4 f1 = *(const float4*)(ap + 4);
          u.x = pk2(f0.x, f0.y); u.y = pk2(f0.z, f0.w);
          u.z = pk2(f1.x, f1.y); u.w = pk2(f1.z, f1.w);
        } else {
          u = *(const uint4*)((const unsigned*)Av + (size_t)gr * 64 + sg * 4);
        }
      } else {
        u = make_uint4(0u, 0u, 0u, 0u);
      }
      *(uint4*)(lds + r * 256 + ((sg * 16) ^ ((r & 7) << 4))) = u;
    }
  }
  // stage Wt (128 rows x 128 bf16)
#pragma unroll
  for (int q = 0; q < 8; q++) {
    int e = t * 8 + q;  // 0..2047
    int n = e >> 4, sg = e & 15;
    uint4 u = *(const uint4*)(Wg + n * 64 + sg * 4);
    *(uint4*)(lds + 16384 + n * 256 + ((sg * 16) ^ ((n & 7) << 4))) = u;
  }
  // stage dinv
  if (t < 64) {
    int gr = row0 + t;
    *(float*)(lds + 49152 + t * 4) = (gr < NN) ? dinv[gr] : 0.f;
  }
  __syncthreads();

  f32x4 acc[4][2];
#pragma unroll
  for (int i = 0; i < 4; i++)
#pragma unroll
    for (int j = 0; j < 2; j++) acc[i][j] = (f32x4){0.f, 0.f, 0.f, 0.f};

#pragma unroll
  for (int kk = 0; kk < 4; kk++) {
    const int koff = (kk * 4 + kb) * 16;  // byte offset of this lane's 8 bf16
    short8 af[4], bf[2];
#pragma unroll
    for (int i = 0; i < 4; i++) {
      int r = i * 16 + lm;
      af[i] = *(const short8*)(lds + r * 256 + (koff ^ ((r & 7) << 4)));
    }
#pragma unroll
    for (int j = 0; j < 2; j++) {
      int n = w * 32 + j * 16 + lm;
      bf[j] = *(const short8*)(lds + 16384 + n * 256 + (koff ^ ((n & 7) << 4)));
    }
#pragma unroll
    for (int i = 0; i < 4; i++)
#pragma unroll
      for (int j = 0; j < 2; j++)
        acc[i][j] = __builtin_amdgcn_mfma_f32_16x16x32_bf16(af[i], bf[j], acc[i][j], 0, 0, 0);
  }

  // epilogue: scale by dinv[row], pack col-pairs via shfl, store uints
#pragma unroll
  for (int i = 0; i < 4; i++) {
#pragma unroll
    for (int j = 0; j < 2; j++) {
#pragma unroll
      for (int q = 0; q < 4; q++) {
        int rl = i * 16 + (l >> 4) * 4 + q;  // local row
        float s = *(const float*)(lds + 49152 + rl * 4);
        float v = acc[i][j][q] * s;
        float nb = __shfl_xor(v, 1);
        if ((l & 1) == 0) {
          int gr = row0 + rl;
          if (gr < NN) {
            int cp = w * 16 + j * 8 + (lm >> 1);
            T[(size_t)gr * 64 + cp] = pk2(v, nb);
          }
        }
      }
    }
  }
}

// ---------------- aggregation ----------------
// out[i] = relu(dinv[i] * (T[i] + sum_{e in CSR[i]} T[src_e]) + b)
template <bool BF16OUT>
__global__ __launch_bounds__(256) void k_agg(const unsigned* __restrict__ T,
                                             const int* __restrict__ offs,
                                             const int* __restrict__ csr,
                                             const float* __restrict__ dinv,
                                             const float* __restrict__ bias,
                                             void* __restrict__ outv) {
  const int lane = threadIdx.x & 63;
  const int node = blockIdx.x * 4 + (threadIdx.x >> 6);
  if (node >= NN) return;
  unsigned su = T[(size_t)node * 64 + lane];  // self-loop term
  float accx = lo_f(su), accy = hi_f(su);
  int j = offs[node];
  const int end = offs[node + 1];
  for (; j + 16 <= end; j += 16) {
    int4 c0 = *(const int4*)(csr + j);
    int4 c1 = *(const int4*)(csr + j + 4);
    int4 c2 = *(const int4*)(csr + j + 8);
    int4 c3 = *(const int4*)(csr + j + 12);
    unsigned u0 = T[(size_t)c0.x * 64 + lane];
    unsigned u1 = T[(size_t)c0.y * 64 + lane];
    unsigned u2 = T[(size_t)c0.z * 64 + lane];
    unsigned u3 = T[(size_t)c0.w * 64 + lane];
    unsigned u4 = T[(size_t)c1.x * 64 + lane];
    unsigned u5 = T[(size_t)c1.y * 64 + lane];
    unsigned u6 = T[(size_t)c1.z * 64 + lane];
    unsigned u7 = T[(size_t)c1.w * 64 + lane];
    unsigned u8 = T[(size_t)c2.x * 64 + lane];
    unsigned u9 = T[(size_t)c2.y * 64 + lane];
    unsigned ua = T[(size_t)c2.z * 64 + lane];
    unsigned ub = T[(size_t)c2.w * 64 + lane];
    unsigned uc = T[(size_t)c3.x * 64 + lane];
    unsigned ud = T[(size_t)c3.y * 64 + lane];
    unsigned ue = T[(size_t)c3.z * 64 + lane];
    unsigned uf = T[(size_t)c3.w * 64 + lane];
    accx += (((lo_f(u0) + lo_f(u1)) + (lo_f(u2) + lo_f(u3))) +
             ((lo_f(u4) + lo_f(u5)) + (lo_f(u6) + lo_f(u7)))) +
            (((lo_f(u8) + lo_f(u9)) + (lo_f(ua) + lo_f(ub))) +
             ((lo_f(uc) + lo_f(ud)) + (lo_f(ue) + lo_f(uf))));
    accy += (((hi_f(u0) + hi_f(u1)) + (hi_f(u2) + hi_f(u3))) +
             ((hi_f(u4) + hi_f(u5)) + (hi_f(u6) + hi_f(u7)))) +
            (((hi_f(u8) + hi_f(u9)) + (hi_f(ua) + hi_f(ub))) +
             ((hi_f(uc) + hi_f(ud)) + (hi_f(ue) + hi_f(uf))));
  }
  for (; j < end; j += 4) {
    int4 c = *(const int4*)(csr + j);
    unsigned u0 = T[(size_t)c.x * 64 + lane];
    unsigned u1 = T[(size_t)c.y * 64 + lane];
    unsigned u2 = T[(size_t)c.z * 64 + lane];
    unsigned u3 = T[(size_t)c.w * 64 + lane];
    accx += (lo_f(u0) + lo_f(u1)) + (lo_f(u2) + lo_f(u3));
    accy += (hi_f(u0) + hi_f(u1)) + (hi_f(u2) + hi_f(u3));
  }
  float s = dinv[node];
  float2 bb = ((const float2*)bias)[lane];
  float ox = fmaxf(accx * s + bb.x, 0.f);
  float oy = fmaxf(accy * s + bb.y, 0.f);
  if (BF16OUT)
    ((unsigned*)outv)[(size_t)node * 64 + lane] = pk2(ox, oy);
  else
    ((float2*)outv)[(size_t)node * 64 + lane] = make_float2(ox, oy);
}

// ---------------- launch ----------------

extern "C" void kernel_launch(void* const* d_in, const int* in_sizes, int n_in,
                              void* d_out, int out_size, void* d_ws, size_t ws_size,
                              hipStream_t stream) {
  const float* x = (const float*)d_in[0];
  const void* ei = (const void*)d_in[1];
  const float* W1 = (const float*)d_in[2];
  const float* b1 = (const float*)d_in[3];
  const float* W2 = (const float*)d_in[4];
  const float* b2 = (const float*)d_in[5];
  const float* W3 = (const float*)d_in[6];
  const float* b3 = (const float*)d_in[7];
  float* out = (float*)d_out;

  char* p = (char*)d_ws;
  auto take = [&](size_t bytes) {
    char* r = p;
    p += (bytes + 1023) & ~(size_t)1023;
    return r;
  };
  int* flagpad = (int*)take(4);  (void)flagpad;
  int* gcur = (int*)take((size_t)NGRP * 4);
  int* scur = (int*)take((size_t)NSUB * 4);
  int* cnt = (int*)take((size_t)NN * 4);
  int* offs = (int*)take((size_t)(NN + 1) * 4);
  int* bsums = (int*)take((size_t)NB * 4);
  float* dinv = (float*)take((size_t)NN * 4);
  unsigned* wt = (unsigned*)take((size_t)3 * DD * 64 * 4);
  int* csr = (int*)take((size_t)CSRCAP * 4);
  // region A: tbuf (25.6MB) overlaid by sub-bucket arrays (14.5MB, dead
  // before first k_gemm writes tbuf)
  char* regA = (char*)take((size_t)(NN + 1) * 64 * 4);
  unsigned* tbuf = (unsigned*)regA;
  int* ssrc = (int*)regA;
  int* sdst = ssrc + (size_t)NSUB * SCAP;  // 2*392*4608*4 = 14.5MB <= 25.6MB
  // region B: hbuf (25.6MB) overlaid by phase-1 buckets (13.4MB, dead
  // before first k_agg writes hbuf)
  char* regB = (char*)take((size_t)NN * 64 * 4);
  unsigned* hbuf = (unsigned*)regB;
  int* bsrc = (int*)regB;
  int* bdst = bsrc + (size_t)NGRP * BCAP;  // 2*8*210000*4 = 13.4MB <= 25.6MB

  const int nb_n = (NN + 255) / 256;

  k_init<<<nb_n, 256, 0, stream>>>(cnt, gcur, scur);
  k_bucket<<<NBLK_B, 256, 0, stream>>>(ei, bsrc, bdst, gcur);
  k_sub<<<128, 256, 0, stream>>>(bsrc, bdst, gcur, cnt, ssrc, sdst, scur);
  k_dinv<<<nb_n, 256, 0, stream>>>(cnt, dinv);
  k_scan1<<<NB, 256, 0, stream>>>(cnt, bsums);
  k_scan2<<<1, 128, 0, stream>>>(bsums, offs);
  k_scan3<<<NB, 256, 0, stream>>>(cnt, bsums, offs);
  k_csr<<<NSUB, 256, 0, stream>>>(ssrc, sdst, scur, offs, csr);
  k_prepw<<<96, 256, 0, stream>>>(W1, W2, W3, wt, tbuf);

  const int gb = (NN + 63) / 64;
  const int ab = (NN + 3) / 4;
  k_gemm<true><<<gb, 256, 0, stream>>>(x, wt, dinv, tbuf);
  k_agg<true><<<ab, 256, 0, stream>>>(tbuf, offs, csr, dinv, b1, hbuf);
  k_gemm<false><<<gb, 256, 0, stream>>>(hbuf, wt + 8192, dinv, tbuf);
  k_agg<true><<<ab, 256, 0, stream>>>(tbuf, offs, csr, dinv, b2, hbuf);
  k_gemm<false><<<gb, 256, 0, stream>>>(hbuf, wt + 16384, dinv, tbuf);
  k_agg<false><<<ab, 256, 0, stream>>>(tbuf, offs, csr, dinv, b3, out);
}

// Round 8
// 415.958 us; speedup vs baseline: 1.2830x; 1.1694x over previous
//
#include <hip/hip_runtime.h>

#define NN 100000
#define NE 1600000
#define DD 128
#define NB 98        // ceil(NN/1024) for the scan
#define NGRP 8       // dst-space partitions
#define NPG (NN / NGRP)         // 12500 nodes per group
#define CSRCAP 1900032          // >= padded total
#define NBLK_B 1024             // bucket-phase blocks
#define EPB 1563                // edges per bucket block (1563*1024 >= NE)
#define BCAP 210000             // per-bucket capacity (mean 200K, 22 sigma)
#define WJ 256                  // dst-window size (nodes)
#define NW 49                   // windows per group = ceil(12500/256)
#define NSUB (NGRP * NW)        // 392 sub-buckets
#define SCAP 4608               // edges per sub-bucket (mean 4096, 8 sigma)
#define LCAP 5632               // padded csr region per window (mean 4480)
#define NSLOT 64                // k_sub slots per group -> 512 blocks

// pk layout: bits 0..16 = src (<2^17), bits 17..30 = dst-in-group (<12500)

typedef __attribute__((ext_vector_type(8))) short short8;
typedef __attribute__((ext_vector_type(4))) float f32x4;

__device__ __forceinline__ unsigned bf16rn(float f) {
  unsigned u = __float_as_uint(f);
  return (u + 0x7fffu + ((u >> 16) & 1u)) >> 16;  // round-to-nearest-even
}
__device__ __forceinline__ unsigned pk2(float a, float b) {
  return bf16rn(a) | (bf16rn(b) << 16);
}
__device__ __forceinline__ float lo_f(unsigned u) { return __uint_as_float(u << 16); }
__device__ __forceinline__ float hi_f(unsigned u) { return __uint_as_float(u & 0xffff0000u); }

// ---------------- preprocessing ----------------

// zero bucket + sub-bucket cursors
__global__ __launch_bounds__(256) void k_init(int* __restrict__ gcur,
                                              int* __restrict__ scur) {
  int i = blockIdx.x * 256 + threadIdx.x;
  if (i < NGRP) gcur[i] = 0;
  if (i < NSUB) scur[i] = 0;
}

// Phase 1: partition edges into 8 dst-range buckets, ONE packed int per edge.
// Per-wave LDS counters (4x less same-address contention), per-wave disjoint
// append sub-ranges inside each (block,bucket) run (~195 ints = 780B).
__global__ __launch_bounds__(256) void k_bucket(const void* __restrict__ ei,
                                                int* __restrict__ bpk,
                                                int* __restrict__ gcur) {
  __shared__ int lcnt[4][NGRP], wbase[4][NGRP], lcur[4][NGRP];
  __shared__ int zcnt;
  const int t = threadIdx.x;
  const int wv = t >> 6;
  if (t == 0) zcnt = 0;
  if (t < 4 * NGRP) { ((int*)lcnt)[t] = 0; ((int*)lcur)[t] = 0; }
  __syncthreads();
  if (t < 64) {
    const unsigned* w = (const unsigned*)ei;
    int z = 0;
    for (int i = t; i < 256; i += 64)
      if (w[2 * i + 1] == 0u) z++;
    atomicAdd(&zcnt, z);
  }
  __syncthreads();
  const int isLL = (zcnt >= 250);
  const long long e0 = (long long)blockIdx.x * EPB;
  const int nE = (int)((NE - e0) < EPB ? (NE - e0) : EPB);
  int epk[7], eb[7];
#pragma unroll
  for (int k = 0; k < 7; k++) {
    int idx = t + k * 256;
    eb[k] = -1;
    if (idx < nE) {
      long long e = e0 + idx;
      int s, d;
      if (isLL) {
        s = (int)((const long long*)ei)[e];
        d = (int)((const long long*)ei)[NE + e];
      } else {
        s = ((const int*)ei)[e];
        d = ((const int*)ei)[NE + e];
      }
      int b = d / NPG;
      eb[k] = b;
      epk[k] = s | ((d - b * NPG) << 17);
      atomicAdd(&lcnt[wv][b], 1);
    }
  }
  __syncthreads();
  if (t < NGRP) {
    int c0 = lcnt[0][t], c1 = lcnt[1][t], c2 = lcnt[2][t], c3 = lcnt[3][t];
    int base = atomicAdd(&gcur[t], c0 + c1 + c2 + c3);
    wbase[0][t] = base;
    wbase[1][t] = base + c0;
    wbase[2][t] = base + c0 + c1;
    wbase[3][t] = base + c0 + c1 + c2;
  }
  __syncthreads();
#pragma unroll
  for (int k = 0; k < 7; k++) {
    if (eb[k] >= 0) {
      int p = wbase[wv][eb[k]] + atomicAdd(&lcur[wv][eb[k]], 1);
      bpk[(size_t)eb[k] * BCAP + p] = epk[k];
    }
  }
}

// Phase 2: split bucket g into 49 windows. 512 blocks (64 slots/group, was
// 128 total -> 5% occupancy). Per-wave counters; single packed write stream,
// runs ~64 ints = 256B.
__global__ __launch_bounds__(256) void k_sub(const int* __restrict__ bpk,
                                             const int* __restrict__ gcur,
                                             int* __restrict__ ssub,
                                             int* __restrict__ scur) {
  __shared__ int lcnt[4][NW], wbase[4][NW], lcur[4][NW];
  const int g = blockIdx.x & (NGRP - 1);
  const int s = blockIdx.x >> 3;  // 0..NSLOT-1
  const int n = gcur[g];
  const int chunk = (n + NSLOT - 1) / NSLOT;
  const int e0 = s * chunk;
  const int e1 = min(e0 + chunk, n);
  const int t = threadIdx.x;
  const int wv = t >> 6;
  for (int i = t; i < 4 * NW; i += 256) { ((int*)lcnt)[i] = 0; ((int*)lcur)[i] = 0; }
  __syncthreads();
  const int* pb = bpk + (size_t)g * BCAP;
  for (int i = e0 + t; i < e1; i += 256)
    atomicAdd(&lcnt[wv][pb[i] >> 25], 1);
  __syncthreads();
  if (t < NW) {
    int c0 = lcnt[0][t], c1 = lcnt[1][t], c2 = lcnt[2][t], c3 = lcnt[3][t];
    int base = atomicAdd(&scur[g * NW + t], c0 + c1 + c2 + c3);
    wbase[0][t] = base;
    wbase[1][t] = base + c0;
    wbase[2][t] = base + c0 + c1;
    wbase[3][t] = base + c0 + c1 + c2;
  }
  __syncthreads();
  for (int i = e0 + t; i < e1; i += 256) {
    int pk = pb[i];
    int w = pk >> 25;
    int p = wbase[wv][w] + atomicAdd(&lcur[wv][w], 1);
    ssub[(size_t)(g * NW + w) * SCAP + p] = pk;
  }
}

// Degree counts per window in LDS, written out sequentially (replaces 1.6M
// scattered global atomics).
__global__ __launch_bounds__(256) void k_cnt(const int* __restrict__ ssub,
                                             const int* __restrict__ scur,
                                             int* __restrict__ cnt) {
  __shared__ int lc[WJ];
  const int b = blockIdx.x;
  const int g = b / NW, w = b % NW;
  const int n0 = g * NPG + w * WJ;
  const int wn = min(WJ, NPG - w * WJ);
  const int t = threadIdx.x;
  lc[t] = 0;
  __syncthreads();
  const int m = scur[b];
  const int* sp = ssub + (size_t)b * SCAP;
  for (int e = t; e < m; e += 256)
    atomicAdd(&lc[(sp[e] >> 17) & 255], 1);
  __syncthreads();
  if (t < wn) cnt[n0 + t] = lc[t];
}

// dinv from degree counts
__global__ __launch_bounds__(256) void k_dinv(const int* __restrict__ cnt,
                                              float* __restrict__ dinv) {
  int i = blockIdx.x * 256 + threadIdx.x;
  if (i < NN) dinv[i] = rsqrtf((float)(cnt[i] + 1));  // +1 self-loop
}

// scans use PADDED counts: pc = (cnt+3) & ~3  (int4-aligned segments)
__global__ __launch_bounds__(256) void k_scan1(const int* __restrict__ cnt,
                                               int* __restrict__ bsums) {
  __shared__ int sd[256];
  const int tid = threadIdx.x;
  const int base = blockIdx.x * 1024;
  int s = 0;
#pragma unroll
  for (int j = 0; j < 4; j++) {
    int i = base + tid * 4 + j;
    if (i < NN) s += (cnt[i] + 3) & ~3;
  }
  sd[tid] = s;
  __syncthreads();
  for (int d = 128; d > 0; d >>= 1) {
    if (tid < d) sd[tid] += sd[tid + d];
    __syncthreads();
  }
  if (tid == 0) bsums[blockIdx.x] = sd[0];
}

__global__ __launch_bounds__(128) void k_scan2(int* __restrict__ bsums,
                                               int* __restrict__ offs) {
  __shared__ int sd[128];
  const int tid = threadIdx.x;
  int v = (tid < NB) ? bsums[tid] : 0;
  sd[tid] = v;
  __syncthreads();
  for (int d = 1; d < 128; d <<= 1) {
    int t = (tid >= d) ? sd[tid - d] : 0;
    __syncthreads();
    sd[tid] += t;
    __syncthreads();
  }
  if (tid < NB) bsums[tid] = sd[tid] - v;  // exclusive
  if (tid == 127) offs[NN] = sd[127];      // padded total
}

__global__ __launch_bounds__(256) void k_scan3(const int* __restrict__ cnt,
                                               const int* __restrict__ bsums,
                                               int* __restrict__ offs) {
  __shared__ int sd[256];
  const int tid = threadIdx.x;
  const int base = blockIdx.x * 1024;
  int v[4];
  int s = 0;
#pragma unroll
  for (int j = 0; j < 4; j++) {
    int i = base + tid * 4 + j;
    v[j] = (i < NN) ? ((cnt[i] + 3) & ~3) : 0;
    s += v[j];
  }
  sd[tid] = s;
  __syncthreads();
  for (int d = 1; d < 256; d <<= 1) {
    int t = (tid >= d) ? sd[tid - d] : 0;
    __syncthreads();
    if (tid >= d) sd[tid] += t;
    __syncthreads();
  }
  int run = bsums[blockIdx.x] + sd[tid] - s;
#pragma unroll
  for (int j = 0; j < 4; j++) {
    int i = base + tid * 4 + j;
    if (i < NN) offs[i] = run;
    run += v[j];
  }
}

// Phase 3: per-window LDS counting-scatter, then ONE sequential coalesced
// write of the whole padded csr region.
__global__ __launch_bounds__(256) void k_csr(const int* __restrict__ ssub,
                                             const int* __restrict__ scur,
                                             const int* __restrict__ offs,
                                             int* __restrict__ csr) {
  __shared__ int L[LCAP];
  __shared__ int loff[WJ], lcur[WJ];
  __shared__ int sR0, sRlen, sm;
  const int b = blockIdx.x;
  const int g = b / NW, w = b % NW;
  const int n0 = g * NPG + w * WJ;
  const int wn = min(WJ, NPG - w * WJ);
  const int t = threadIdx.x;
  for (int i = t; i < LCAP; i += 256) L[i] = NN;  // dummy zero-row index
  if (t == 0) {
    sR0 = offs[n0];
    sRlen = offs[n0 + wn] - sR0;
    sm = scur[b];
  }
  __syncthreads();
  const int R0 = sR0, Rlen = sRlen, m = sm;
  for (int i = t; i < wn; i += 256) {
    loff[i] = offs[n0 + i] - R0;
    lcur[i] = 0;
  }
  __syncthreads();
  const int* sp = ssub + (size_t)b * SCAP;
  for (int e = t; e < m; e += 256) {
    int pk = sp[e];
    int dl = (pk >> 17) & 255;
    int pos = loff[dl] + atomicAdd(&lcur[dl], 1);
    if (pos < LCAP) L[pos] = pk & 0x1FFFF;
  }
  __syncthreads();
  for (int i = t * 4; i < Rlen; i += 1024)
    if (i + 3 < LCAP) *(int4*)(csr + R0 + i) = *(const int4*)&L[i];
}

// Wt[n][k] = bf16(W[k][n]) all 3 layers; also zero the dummy T row (row NN)
__global__ __launch_bounds__(256) void k_prepw(const float* __restrict__ Wa,
                                               const float* __restrict__ Wb,
                                               const float* __restrict__ Wc,
                                               unsigned* __restrict__ wt,
                                               unsigned* __restrict__ tbuf) {
  if (blockIdx.x == 0 && threadIdx.x < 64)
    tbuf[(size_t)NN * 64 + threadIdx.x] = 0u;
  int id = blockIdx.x * 256 + threadIdx.x;  // 0..24575
  int layer = id >> 13;                     // 8192 per layer
  int r = id & 8191;
  int n = r >> 6, kp = r & 63;
  const float* W = (layer == 0) ? Wa : (layer == 1) ? Wb : Wc;
  wt[(size_t)layer * 8192 + n * 64 + kp] =
      pk2(W[(size_t)(2 * kp) * DD + n], W[(size_t)(2 * kp + 1) * DD + n]);
}

// ---------------- MFMA GEMM:  T[r][:] = bf16( (A[r][:] @ W) * dinv[r] ) ----
template <bool F32SRC>
__global__ __launch_bounds__(256) void k_gemm(const void* __restrict__ Av,
                                              const unsigned* __restrict__ Wg,
                                              const float* __restrict__ dinv,
                                              unsigned* __restrict__ T) {
  __shared__ char lds[49408];  // 0:A(16K) 16384:Wt(32K) 49152:dinv(256B)
  const int t = threadIdx.x;
  const int row0 = blockIdx.x * 64;
  const int w = t >> 6, l = t & 63;
  const int lm = l & 15, kb = l >> 4;

  // stage A tile (64 rows x 128 bf16)
  {
    int r = t >> 2;
    int gr = row0 + r;
#pragma unroll
    for (int s4 = 0; s4 < 4; s4++) {
      int sg = (t & 3) * 4 + s4;  // 16B segment 0..15
      uint4 u;
      if (gr < NN) {
        if (F32SRC) {
          const float* ap = (const float*)Av + (size_t)gr * DD + sg * 8;
          float4 f0 = *(const float4*)ap;
          float4 f1 = *(const float4*)(ap + 4);
          u.x = pk2(f0.x, f0.y); u.y = pk2(f0.z, f0.w);
          u.z = pk2(f1.x, f1.y); u.w = pk2(f1.z, f1.w);
        } else {
          u = *(const uint4*)((const unsigned*)Av + (size_t)gr * 64 + sg * 4);
        }
      } else {
        u = make_uint4(0u, 0u, 0u, 0u);
      }
      *(uint4*)(lds + r * 256 + ((sg * 16) ^ ((r & 7) << 4))) = u;
    }
  }
  // stage Wt (128 rows x 128 bf16)
#pragma unroll
  for (int q = 0; q < 8; q++) {
    int e = t * 8 + q;  // 0..2047
    int n = e >> 4, sg = e & 15;
    uint4 u = *(const uint4*)(Wg + n * 64 + sg * 4);
    *(uint4*)(lds + 16384 + n * 256 + ((sg * 16) ^ ((n & 7) << 4))) = u;
  }
  // stage dinv
  if (t < 64) {
    int gr = row0 + t;
    *(float*)(lds + 49152 + t * 4) = (gr < NN) ? dinv[gr] : 0.f;
  }
  __syncthreads();

  f32x4 acc[4][2];
#pragma unroll
  for (int i = 0; i < 4; i++)
#pragma unroll
    for (int j = 0; j < 2; j++) acc[i][j] = (f32x4){0.f, 0.f, 0.f, 0.f};

#pragma unroll
  for (int kk = 0; kk < 4; kk++) {
    const int koff = (kk * 4 + kb) * 16;  // byte offset of this lane's 8 bf16
    short8 af[4], bf[2];
#pragma unroll
    for (int i = 0; i < 4; i++) {
      int r = i * 16 + lm;
      af[i] = *(const short8*)(lds + r * 256 + (koff ^ ((r & 7) << 4)));
    }
#pragma unroll
    for (int j = 0; j < 2; j++) {
      int n = w * 32 + j * 16 + lm;
      bf[j] = *(const short8*)(lds + 16384 + n * 256 + (koff ^ ((n & 7) << 4)));
    }
#pragma unroll
    for (int i = 0; i < 4; i++)
#pragma unroll
      for (int j = 0; j < 2; j++)
        acc[i][j] = __builtin_amdgcn_mfma_f32_16x16x32_bf16(af[i], bf[j], acc[i][j], 0, 0, 0);
  }

  // epilogue: scale by dinv[row], pack col-pairs via shfl, store uints
#pragma unroll
  for (int i = 0; i < 4; i++) {
#pragma unroll
    for (int j = 0; j < 2; j++) {
#pragma unroll
      for (int q = 0; q < 4; q++) {
        int rl = i * 16 + (l >> 4) * 4 + q;  // local row
        float s = *(const float*)(lds + 49152 + rl * 4);
        float v = acc[i][j][q] * s;
        float nb = __shfl_xor(v, 1);
        if ((l & 1) == 0) {
          int gr = row0 + rl;
          if (gr < NN) {
            int cp = w * 16 + j * 8 + (lm >> 1);
            T[(size_t)gr * 64 + cp] = pk2(v, nb);
          }
        }
      }
    }
  }
}

// ---------------- aggregation ----------------
// out[i] = relu(dinv[i] * (T[i] + sum_{e in CSR[i]} T[src_e]) + b)
template <bool BF16OUT>
__global__ __launch_bounds__(256) void k_agg(const unsigned* __restrict__ T,
                                             const int* __restrict__ offs,
                                             const int* __restrict__ csr,
                                             const float* __restrict__ dinv,
                                             const float* __restrict__ bias,
                                             void* __restrict__ outv) {
  const int lane = threadIdx.x & 63;
  const int node = blockIdx.x * 4 + (threadIdx.x >> 6);
  if (node >= NN) return;
  unsigned su = T[(size_t)node * 64 + lane];  // self-loop term
  float accx = lo_f(su), accy = hi_f(su);
  int j = offs[node];
  const int end = offs[node + 1];
  for (; j + 16 <= end; j += 16) {
    int4 c0 = *(const int4*)(csr + j);
    int4 c1 = *(const int4*)(csr + j + 4);
    int4 c2 = *(const int4*)(csr + j + 8);
    int4 c3 = *(const int4*)(csr + j + 12);
    unsigned u0 = T[(size_t)c0.x * 64 + lane];
    unsigned u1 = T[(size_t)c0.y * 64 + lane];
    unsigned u2 = T[(size_t)c0.z * 64 + lane];
    unsigned u3 = T[(size_t)c0.w * 64 + lane];
    unsigned u4 = T[(size_t)c1.x * 64 + lane];
    unsigned u5 = T[(size_t)c1.y * 64 + lane];
    unsigned u6 = T[(size_t)c1.z * 64 + lane];
    unsigned u7 = T[(size_t)c1.w * 64 + lane];
    unsigned u8 = T[(size_t)c2.x * 64 + lane];
    unsigned u9 = T[(size_t)c2.y * 64 + lane];
    unsigned ua = T[(size_t)c2.z * 64 + lane];
    unsigned ub = T[(size_t)c2.w * 64 + lane];
    unsigned uc = T[(size_t)c3.x * 64 + lane];
    unsigned ud = T[(size_t)c3.y * 64 + lane];
    unsigned ue = T[(size_t)c3.z * 64 + lane];
    unsigned uf = T[(size_t)c3.w * 64 + lane];
    accx += (((lo_f(u0) + lo_f(u1)) + (lo_f(u2) + lo_f(u3))) +
             ((lo_f(u4) + lo_f(u5)) + (lo_f(u6) + lo_f(u7)))) +
            (((lo_f(u8) + lo_f(u9)) + (lo_f(ua) + lo_f(ub))) +
             ((lo_f(uc) + lo_f(ud)) + (lo_f(ue) + lo_f(uf))));
    accy += (((hi_f(u0) + hi_f(u1)) + (hi_f(u2) + hi_f(u3))) +
             ((hi_f(u4) + hi_f(u5)) + (hi_f(u6) + hi_f(u7)))) +
            (((hi_f(u8) + hi_f(u9)) + (hi_f(ua) + hi_f(ub))) +
             ((hi_f(uc) + hi_f(ud)) + (hi_f(ue) + hi_f(uf))));
  }
  for (; j < end; j += 4) {
    int4 c = *(const int4*)(csr + j);
    unsigned u0 = T[(size_t)c.x * 64 + lane];
    unsigned u1 = T[(size_t)c.y * 64 + lane];
    unsigned u2 = T[(size_t)c.z * 64 + lane];
    unsigned u3 = T[(size_t)c.w * 64 + lane];
    accx += (lo_f(u0) + lo_f(u1)) + (lo_f(u2) + lo_f(u3));
    accy += (hi_f(u0) + hi_f(u1)) + (hi_f(u2) + hi_f(u3));
  }
  float s = dinv[node];
  float2 bb = ((const float2*)bias)[lane];
  float ox = fmaxf(accx * s + bb.x, 0.f);
  float oy = fmaxf(accy * s + bb.y, 0.f);
  if (BF16OUT)
    ((unsigned*)outv)[(size_t)node * 64 + lane] = pk2(ox, oy);
  else
    ((float2*)outv)[(size_t)node * 64 + lane] = make_float2(ox, oy);
}

// ---------------- launch ----------------

extern "C" void kernel_launch(void* const* d_in, const int* in_sizes, int n_in,
                              void* d_out, int out_size, void* d_ws, size_t ws_size,
                              hipStream_t stream) {
  const float* x = (const float*)d_in[0];
  const void* ei = (const void*)d_in[1];
  const float* W1 = (const float*)d_in[2];
  const float* b1 = (const float*)d_in[3];
  const float* W2 = (const float*)d_in[4];
  const float* b2 = (const float*)d_in[5];
  const float* W3 = (const float*)d_in[6];
  const float* b3 = (const float*)d_in[7];
  float* out = (float*)d_out;

  char* p = (char*)d_ws;
  auto take = [&](size_t bytes) {
    char* r = p;
    p += (bytes + 1023) & ~(size_t)1023;
    return r;
  };
  int* gcur = (int*)take((size_t)NGRP * 4);
  int* scur = (int*)take((size_t)NSUB * 4);
  int* cnt = (int*)take((size_t)NN * 4);
  int* offs = (int*)take((size_t)(NN + 1) * 4);
  int* bsums = (int*)take((size_t)NB * 4);
  float* dinv = (float*)take((size_t)NN * 4);
  unsigned* wt = (unsigned*)take((size_t)3 * DD * 64 * 4);
  int* csr = (int*)take((size_t)CSRCAP * 4);
  // region A: tbuf (25.6MB) overlaid by packed sub-buckets (7.2MB, dead
  // before first k_gemm writes tbuf)
  char* regA = (char*)take((size_t)(NN + 1) * 64 * 4);
  unsigned* tbuf = (unsigned*)regA;
  int* ssub = (int*)regA;  // 392*4608*4 = 7.2MB
  // region B: hbuf (25.6MB) overlaid by packed phase-1 buckets (6.7MB, dead
  // before first k_agg writes hbuf)
  char* regB = (char*)take((size_t)NN * 64 * 4);
  unsigned* hbuf = (unsigned*)regB;
  int* bpk = (int*)regB;  // 8*210000*4 = 6.7MB

  const int nb_n = (NN + 255) / 256;

  k_init<<<2, 256, 0, stream>>>(gcur, scur);
  k_bucket<<<NBLK_B, 256, 0, stream>>>(ei, bpk, gcur);
  k_sub<<<NGRP * NSLOT, 256, 0, stream>>>(bpk, gcur, ssub, scur);
  k_cnt<<<NSUB, 256, 0, stream>>>(ssub, scur, cnt);
  k_dinv<<<nb_n, 256, 0, stream>>>(cnt, dinv);
  k_scan1<<<NB, 256, 0, stream>>>(cnt, bsums);
  k_scan2<<<1, 128, 0, stream>>>(bsums, offs);
  k_scan3<<<NB, 256, 0, stream>>>(cnt, bsums, offs);
  k_csr<<<NSUB, 256, 0, stream>>>(ssub, scur, offs, csr);
  k_prepw<<<96, 256, 0, stream>>>(W1, W2, W3, wt, tbuf);

  const int gb = (NN + 63) / 64;
  const int ab = (NN + 3) / 4;
  k_gemm<true><<<gb, 256, 0, stream>>>(x, wt, dinv, tbuf);
  k_agg<true><<<ab, 256, 0, stream>>>(tbuf, offs, csr, dinv, b1, hbuf);
  k_gemm<false><<<gb, 256, 0, stream>>>(hbuf, wt + 8192, dinv, tbuf);
  k_agg<true><<<ab, 256, 0, stream>>>(tbuf, offs, csr, dinv, b2, hbuf);
  k_gemm<false><<<gb, 256, 0, stream>>>(hbuf, wt + 16384, dinv, tbuf);
  k_agg<false><<<ab, 256, 0, stream>>>(tbuf, offs, csr, dinv, b3, out);
}

// Round 9
// 406.283 us; speedup vs baseline: 1.3135x; 1.0238x over previous
//
#include <hip/hip_runtime.h>

#define NN 100000
#define NE 1600000
#define DD 128
#define NGRP 8       // dst-space partitions
#define NPG (NN / NGRP)         // 12500 nodes per group
#define CSRCAP 1900032          // >= padded total
#define NBLK_B 1024             // bucket-phase blocks
#define EPB 1563                // edges per bucket block (1563*1024 >= NE)
#define BCAP 210000             // per-bucket capacity (mean 200K, 22 sigma)
#define WJ 256                  // dst-window size (nodes)
#define NW 49                   // windows per group = ceil(12500/256)
#define NSUB (NGRP * NW)        // 392 sub-buckets
#define SCAP 4608               // edges per sub-bucket (mean 4096, 8 sigma)
#define LCAP 5632               // padded csr region per window (mean 4480)
#define NSLOT 64                // k_sub slots per group -> 512 blocks

// pk layout: bits 0..16 = src (<2^17), bits 17..30 = dst-in-group (<12500)

typedef __attribute__((ext_vector_type(8))) short short8;
typedef __attribute__((ext_vector_type(4))) float f32x4;

__device__ __forceinline__ unsigned bf16rn(float f) {
  unsigned u = __float_as_uint(f);
  return (u + 0x7fffu + ((u >> 16) & 1u)) >> 16;  // round-to-nearest-even
}
__device__ __forceinline__ unsigned pk2(float a, float b) {
  return bf16rn(a) | (bf16rn(b) << 16);
}
__device__ __forceinline__ float lo_f(unsigned u) { return __uint_as_float(u << 16); }
__device__ __forceinline__ float hi_f(unsigned u) { return __uint_as_float(u & 0xffff0000u); }

// ---------------- preprocessing ----------------

// blocks 0..95: Wt[n][k] = bf16(W[k][n]) for 3 layers.
// block 96: zero cursors + dummy T row.
__global__ __launch_bounds__(256) void k_initw(const float* __restrict__ Wa,
                                               const float* __restrict__ Wb,
                                               const float* __restrict__ Wc,
                                               unsigned* __restrict__ wt,
                                               unsigned* __restrict__ tbuf,
                                               int* __restrict__ gcur,
                                               int* __restrict__ scur) {
  const int t = threadIdx.x;
  if (blockIdx.x == 96) {
    if (t < NGRP) gcur[t] = 0;
    for (int i = t; i < NSUB; i += 256) scur[i] = 0;
    if (t < 64) tbuf[(size_t)NN * 64 + t] = 0u;
    return;
  }
  int id = blockIdx.x * 256 + t;  // 0..24575
  int layer = id >> 13;           // 8192 per layer
  int r = id & 8191;
  int n = r >> 6, kp = r & 63;
  const float* W = (layer == 0) ? Wa : (layer == 1) ? Wb : Wc;
  wt[(size_t)layer * 8192 + n * 64 + kp] =
      pk2(W[(size_t)(2 * kp) * DD + n], W[(size_t)(2 * kp + 1) * DD + n]);
}

// Phase 1: partition edges into 8 dst-range buckets, ONE packed int per edge.
__global__ __launch_bounds__(256) void k_bucket(const void* __restrict__ ei,
                                                int* __restrict__ bpk,
                                                int* __restrict__ gcur) {
  __shared__ int lcnt[4][NGRP], wbase[4][NGRP], lcur[4][NGRP];
  __shared__ int zcnt;
  const int t = threadIdx.x;
  const int wv = t >> 6;
  if (t == 0) zcnt = 0;
  if (t < 4 * NGRP) { ((int*)lcnt)[t] = 0; ((int*)lcur)[t] = 0; }
  __syncthreads();
  if (t < 64) {
    const unsigned* w = (const unsigned*)ei;
    int z = 0;
    for (int i = t; i < 256; i += 64)
      if (w[2 * i + 1] == 0u) z++;
    atomicAdd(&zcnt, z);
  }
  __syncthreads();
  const int isLL = (zcnt >= 250);
  const long long e0 = (long long)blockIdx.x * EPB;
  const int nE = (int)((NE - e0) < EPB ? (NE - e0) : EPB);
  int epk[7], eb[7];
#pragma unroll
  for (int k = 0; k < 7; k++) {
    int idx = t + k * 256;
    eb[k] = -1;
    if (idx < nE) {
      long long e = e0 + idx;
      int s, d;
      if (isLL) {
        s = (int)((const long long*)ei)[e];
        d = (int)((const long long*)ei)[NE + e];
      } else {
        s = ((const int*)ei)[e];
        d = ((const int*)ei)[NE + e];
      }
      int b = d / NPG;
      eb[k] = b;
      epk[k] = s | ((d - b * NPG) << 17);
      atomicAdd(&lcnt[wv][b], 1);
    }
  }
  __syncthreads();
  if (t < NGRP) {
    int c0 = lcnt[0][t], c1 = lcnt[1][t], c2 = lcnt[2][t], c3 = lcnt[3][t];
    int base = atomicAdd(&gcur[t], c0 + c1 + c2 + c3);
    wbase[0][t] = base;
    wbase[1][t] = base + c0;
    wbase[2][t] = base + c0 + c1;
    wbase[3][t] = base + c0 + c1 + c2;
  }
  __syncthreads();
#pragma unroll
  for (int k = 0; k < 7; k++) {
    if (eb[k] >= 0) {
      int p = wbase[wv][eb[k]] + atomicAdd(&lcur[wv][eb[k]], 1);
      bpk[(size_t)eb[k] * BCAP + p] = epk[k];
    }
  }
}

// Phase 2: split bucket g into 49 windows; 512 blocks, per-wave counters.
__global__ __launch_bounds__(256) void k_sub(const int* __restrict__ bpk,
                                             const int* __restrict__ gcur,
                                             int* __restrict__ ssub,
                                             int* __restrict__ scur) {
  __shared__ int lcnt[4][NW], wbase[4][NW], lcur[4][NW];
  const int g = blockIdx.x & (NGRP - 1);
  const int s = blockIdx.x >> 3;  // 0..NSLOT-1
  const int n = gcur[g];
  const int chunk = (n + NSLOT - 1) / NSLOT;
  const int e0 = s * chunk;
  const int e1 = min(e0 + chunk, n);
  const int t = threadIdx.x;
  const int wv = t >> 6;
  for (int i = t; i < 4 * NW; i += 256) { ((int*)lcnt)[i] = 0; ((int*)lcur)[i] = 0; }
  __syncthreads();
  const int* pb = bpk + (size_t)g * BCAP;
  for (int i = e0 + t; i < e1; i += 256)
    atomicAdd(&lcnt[wv][pb[i] >> 25], 1);
  __syncthreads();
  if (t < NW) {
    int c0 = lcnt[0][t], c1 = lcnt[1][t], c2 = lcnt[2][t], c3 = lcnt[3][t];
    int base = atomicAdd(&scur[g * NW + t], c0 + c1 + c2 + c3);
    wbase[0][t] = base;
    wbase[1][t] = base + c0;
    wbase[2][t] = base + c0 + c1;
    wbase[3][t] = base + c0 + c1 + c2;
  }
  __syncthreads();
  for (int i = e0 + t; i < e1; i += 256) {
    int pk = pb[i];
    int w = pk >> 25;
    int p = wbase[wv][w] + atomicAdd(&lcur[wv][w], 1);
    ssub[(size_t)(g * NW + w) * SCAP + p] = pk;
  }
}

// Per-window degree count in LDS -> dinv (coalesced) + padded window sum.
// Replaces the cnt array, k_dinv, and k_scan1.
__global__ __launch_bounds__(256) void k_cntd(const int* __restrict__ ssub,
                                              const int* __restrict__ scur,
                                              float* __restrict__ dinv,
                                              int* __restrict__ wsum) {
  __shared__ int lc[WJ];
  __shared__ int sd[256];
  const int b = blockIdx.x;
  const int g = b / NW, w = b % NW;
  const int n0 = g * NPG + w * WJ;
  const int wn = min(WJ, NPG - w * WJ);
  const int t = threadIdx.x;
  lc[t] = 0;
  __syncthreads();
  const int m = scur[b];
  const int* sp = ssub + (size_t)b * SCAP;
  for (int e = t; e < m; e += 256)
    atomicAdd(&lc[(sp[e] >> 17) & 255], 1);
  __syncthreads();
  if (t < wn) dinv[n0 + t] = rsqrtf((float)(lc[t] + 1));  // +1 self-loop
  sd[t] = (t < wn) ? ((lc[t] + 3) & ~3) : 0;
  __syncthreads();
  for (int d = 128; d > 0; d >>= 1) {
    if (t < d) sd[t] += sd[t + d];
    __syncthreads();
  }
  if (t == 0) wsum[b] = sd[0];
}

// Exclusive scan of the 392 padded window sums -> wbase; offs[NN] = total.
__global__ __launch_bounds__(512) void k_scan2(const int* __restrict__ wsum,
                                               int* __restrict__ wbase,
                                               int* __restrict__ offs) {
  __shared__ int sd[512];
  const int t = threadIdx.x;
  int v = (t < NSUB) ? wsum[t] : 0;
  sd[t] = v;
  __syncthreads();
  for (int d = 1; d < 512; d <<= 1) {
    int x = (t >= d) ? sd[t - d] : 0;
    __syncthreads();
    sd[t] += x;
    __syncthreads();
  }
  if (t < NSUB) wbase[t] = sd[t] - v;  // exclusive
  if (t == 511) offs[NN] = sd[511];    // padded total
}

// Phase 3: per-window count -> LDS exclusive scan -> LDS counting-scatter ->
// sequential coalesced writes of offs AND the whole padded csr region.
// (Replaces k_scan3 + old k_csr; no scattered global stores anywhere.)
__global__ __launch_bounds__(256) void k_csr(const int* __restrict__ ssub,
                                             const int* __restrict__ scur,
                                             const int* __restrict__ wbase,
                                             int* __restrict__ offs,
                                             int* __restrict__ csr) {
  __shared__ int L[LCAP];
  __shared__ int lc[WJ], lcur[WJ], sc[256];
  const int b = blockIdx.x;
  const int g = b / NW, w = b % NW;
  const int n0 = g * NPG + w * WJ;
  const int wn = min(WJ, NPG - w * WJ);
  const int t = threadIdx.x;
  lc[t] = 0;
  lcur[t] = 0;
  for (int i = t; i < LCAP; i += 256) L[i] = NN;  // dummy zero-row index
  __syncthreads();
  const int m = scur[b];
  const int R0 = wbase[b];
  const int* sp = ssub + (size_t)b * SCAP;
  for (int e = t; e < m; e += 256)
    atomicAdd(&lc[(sp[e] >> 17) & 255], 1);
  __syncthreads();
  int v = (lc[t] + 3) & ~3;  // padded count (0 for t>=wn since lc=0)
  sc[t] = v;
  __syncthreads();
  for (int d = 1; d < 256; d <<= 1) {
    int x = (t >= d) ? sc[t - d] : 0;
    __syncthreads();
    sc[t] += x;
    __syncthreads();
  }
  int excl = sc[t] - v;
  if (t < wn) offs[n0 + t] = R0 + excl;
  lc[t] = excl;  // reuse as local segment base
  __syncthreads();
  for (int e = t; e < m; e += 256) {
    int pk = sp[e];
    int dl = (pk >> 17) & 255;
    int pos = lc[dl] + atomicAdd(&lcur[dl], 1);
    L[pos] = pk & 0x1FFFF;
  }
  __syncthreads();
  const int Rlen = sc[255];
  for (int i = t * 4; i < Rlen; i += 1024)
    *(int4*)(csr + R0 + i) = *(const int4*)&L[i];
}

// ---------------- MFMA GEMM:  T[r][:] = bf16( (A[r][:] @ W) * dinv[r] ) ----
template <bool F32SRC>
__global__ __launch_bounds__(256) void k_gemm(const void* __restrict__ Av,
                                              const unsigned* __restrict__ Wg,
                                              const float* __restrict__ dinv,
                                              unsigned* __restrict__ T) {
  __shared__ char lds[49408];  // 0:A(16K) 16384:Wt(32K) 49152:dinv(256B)
  const int t = threadIdx.x;
  const int row0 = blockIdx.x * 64;
  const int w = t >> 6, l = t & 63;
  const int lm = l & 15, kb = l >> 4;

  // stage A tile (64 rows x 128 bf16)
  {
    int r = t >> 2;
    int gr = row0 + r;
#pragma unroll
    for (int s4 = 0; s4 < 4; s4++) {
      int sg = (t & 3) * 4 + s4;  // 16B segment 0..15
      uint4 u;
      if (gr < NN) {
        if (F32SRC) {
          const float* ap = (const float*)Av + (size_t)gr * DD + sg * 8;
          float4 f0 = *(const float4*)ap;
          float4 f1 = *(const float4*)(ap + 4);
          u.x = pk2(f0.x, f0.y); u.y = pk2(f0.z, f0.w);
          u.z = pk2(f1.x, f1.y); u.w = pk2(f1.z, f1.w);
        } else {
          u = *(const uint4*)((const unsigned*)Av + (size_t)gr * 64 + sg * 4);
        }
      } else {
        u = make_uint4(0u, 0u, 0u, 0u);
      }
      *(uint4*)(lds + r * 256 + ((sg * 16) ^ ((r & 7) << 4))) = u;
    }
  }
  // stage Wt (128 rows x 128 bf16)
#pragma unroll
  for (int q = 0; q < 8; q++) {
    int e = t * 8 + q;  // 0..2047
    int n = e >> 4, sg = e & 15;
    uint4 u = *(const uint4*)(Wg + n * 64 + sg * 4);
    *(uint4*)(lds + 16384 + n * 256 + ((sg * 16) ^ ((n & 7) << 4))) = u;
  }
  // stage dinv
  if (t < 64) {
    int gr = row0 + t;
    *(float*)(lds + 49152 + t * 4) = (gr < NN) ? dinv[gr] : 0.f;
  }
  __syncthreads();

  f32x4 acc[4][2];
#pragma unroll
  for (int i = 0; i < 4; i++)
#pragma unroll
    for (int j = 0; j < 2; j++) acc[i][j] = (f32x4){0.f, 0.f, 0.f, 0.f};

#pragma unroll
  for (int kk = 0; kk < 4; kk++) {
    const int koff = (kk * 4 + kb) * 16;  // byte offset of this lane's 8 bf16
    short8 af[4], bf[2];
#pragma unroll
    for (int i = 0; i < 4; i++) {
      int r = i * 16 + lm;
      af[i] = *(const short8*)(lds + r * 256 + (koff ^ ((r & 7) << 4)));
    }
#pragma unroll
    for (int j = 0; j < 2; j++) {
      int n = w * 32 + j * 16 + lm;
      bf[j] = *(const short8*)(lds + 16384 + n * 256 + (koff ^ ((n & 7) << 4)));
    }
#pragma unroll
    for (int i = 0; i < 4; i++)
#pragma unroll
      for (int j = 0; j < 2; j++)
        acc[i][j] = __builtin_amdgcn_mfma_f32_16x16x32_bf16(af[i], bf[j], acc[i][j], 0, 0, 0);
  }

  // epilogue: scale by dinv[row], pack col-pairs via shfl, store uints
#pragma unroll
  for (int i = 0; i < 4; i++) {
#pragma unroll
    for (int j = 0; j < 2; j++) {
#pragma unroll
      for (int q = 0; q < 4; q++) {
        int rl = i * 16 + (l >> 4) * 4 + q;  // local row
        float s = *(const float*)(lds + 49152 + rl * 4);
        float v = acc[i][j][q] * s;
        float nb = __shfl_xor(v, 1);
        if ((l & 1) == 0) {
          int gr = row0 + rl;
          if (gr < NN) {
            int cp = w * 16 + j * 8 + (lm >> 1);
            T[(size_t)gr * 64 + cp] = pk2(v, nb);
          }
        }
      }
    }
  }
}

// ---------------- aggregation ----------------
// out[i] = relu(dinv[i] * (T[i] + sum_{e in CSR[i]} T[src_e]) + b)
template <bool BF16OUT>
__global__ __launch_bounds__(256) void k_agg(const unsigned* __restrict__ T,
                                             const int* __restrict__ offs,
                                             const int* __restrict__ csr,
                                             const float* __restrict__ dinv,
                                             const float* __restrict__ bias,
                                             void* __restrict__ outv) {
  const int lane = threadIdx.x & 63;
  const int node = blockIdx.x * 4 + (threadIdx.x >> 6);
  if (node >= NN) return;
  unsigned su = T[(size_t)node * 64 + lane];  // self-loop term
  float accx = lo_f(su), accy = hi_f(su);
  int j = offs[node];
  const int end = offs[node + 1];
  for (; j + 16 <= end; j += 16) {
    int4 c0 = *(const int4*)(csr + j);
    int4 c1 = *(const int4*)(csr + j + 4);
    int4 c2 = *(const int4*)(csr + j + 8);
    int4 c3 = *(const int4*)(csr + j + 12);
    unsigned u0 = T[(size_t)c0.x * 64 + lane];
    unsigned u1 = T[(size_t)c0.y * 64 + lane];
    unsigned u2 = T[(size_t)c0.z * 64 + lane];
    unsigned u3 = T[(size_t)c0.w * 64 + lane];
    unsigned u4 = T[(size_t)c1.x * 64 + lane];
    unsigned u5 = T[(size_t)c1.y * 64 + lane];
    unsigned u6 = T[(size_t)c1.z * 64 + lane];
    unsigned u7 = T[(size_t)c1.w * 64 + lane];
    unsigned u8 = T[(size_t)c2.x * 64 + lane];
    unsigned u9 = T[(size_t)c2.y * 64 + lane];
    unsigned ua = T[(size_t)c2.z * 64 + lane];
    unsigned ub = T[(size_t)c2.w * 64 + lane];
    unsigned uc = T[(size_t)c3.x * 64 + lane];
    unsigned ud = T[(size_t)c3.y * 64 + lane];
    unsigned ue = T[(size_t)c3.z * 64 + lane];
    unsigned uf = T[(size_t)c3.w * 64 + lane];
    accx += (((lo_f(u0) + lo_f(u1)) + (lo_f(u2) + lo_f(u3))) +
             ((lo_f(u4) + lo_f(u5)) + (lo_f(u6) + lo_f(u7)))) +
            (((lo_f(u8) + lo_f(u9)) + (lo_f(ua) + lo_f(ub))) +
             ((lo_f(uc) + lo_f(ud)) + (lo_f(ue) + lo_f(uf))));
    accy += (((hi_f(u0) + hi_f(u1)) + (hi_f(u2) + hi_f(u3))) +
             ((hi_f(u4) + hi_f(u5)) + (hi_f(u6) + hi_f(u7)))) +
            (((hi_f(u8) + hi_f(u9)) + (hi_f(ua) + hi_f(ub))) +
             ((hi_f(uc) + hi_f(ud)) + (hi_f(ue) + hi_f(uf))));
  }
  for (; j < end; j += 4) {
    int4 c = *(const int4*)(csr + j);
    unsigned u0 = T[(size_t)c.x * 64 + lane];
    unsigned u1 = T[(size_t)c.y * 64 + lane];
    unsigned u2 = T[(size_t)c.z * 64 + lane];
    unsigned u3 = T[(size_t)c.w * 64 + lane];
    accx += (lo_f(u0) + lo_f(u1)) + (lo_f(u2) + lo_f(u3));
    accy += (hi_f(u0) + hi_f(u1)) + (hi_f(u2) + hi_f(u3));
  }
  float s = dinv[node];
  float2 bb = ((const float2*)bias)[lane];
  float ox = fmaxf(accx * s + bb.x, 0.f);
  float oy = fmaxf(accy * s + bb.y, 0.f);
  if (BF16OUT)
    ((unsigned*)outv)[(size_t)node * 64 + lane] = pk2(ox, oy);
  else
    ((float2*)outv)[(size_t)node * 64 + lane] = make_float2(ox, oy);
}

// ---------------- launch ----------------

extern "C" void kernel_launch(void* const* d_in, const int* in_sizes, int n_in,
                              void* d_out, int out_size, void* d_ws, size_t ws_size,
                              hipStream_t stream) {
  const float* x = (const float*)d_in[0];
  const void* ei = (const void*)d_in[1];
  const float* W1 = (const float*)d_in[2];
  const float* b1 = (const float*)d_in[3];
  const float* W2 = (const float*)d_in[4];
  const float* b2 = (const float*)d_in[5];
  const float* W3 = (const float*)d_in[6];
  const float* b3 = (const float*)d_in[7];
  float* out = (float*)d_out;

  char* p = (char*)d_ws;
  auto take = [&](size_t bytes) {
    char* r = p;
    p += (bytes + 1023) & ~(size_t)1023;
    return r;
  };
  int* gcur = (int*)take((size_t)NGRP * 4);
  int* scur = (int*)take((size_t)NSUB * 4);
  int* wsum = (int*)take((size_t)NSUB * 4);
  int* wbase = (int*)take((size_t)NSUB * 4);
  int* offs = (int*)take((size_t)(NN + 1) * 4);
  float* dinv = (float*)take((size_t)NN * 4);
  unsigned* wt = (unsigned*)take((size_t)3 * DD * 64 * 4);
  int* csr = (int*)take((size_t)CSRCAP * 4);
  // region A: tbuf (25.6MB+row) overlaid by packed sub-buckets (7.2MB, dead
  // before first k_gemm writes tbuf; dummy row at 25.6MB is past ssub)
  char* regA = (char*)take((size_t)(NN + 1) * 64 * 4);
  unsigned* tbuf = (unsigned*)regA;
  int* ssub = (int*)regA;  // 392*4608*4 = 7.2MB
  // region B: hbuf (25.6MB) overlaid by packed phase-1 buckets (6.7MB, dead
  // before first k_agg writes hbuf)
  char* regB = (char*)take((size_t)NN * 64 * 4);
  unsigned* hbuf = (unsigned*)regB;
  int* bpk = (int*)regB;  // 8*210000*4 = 6.7MB

  k_initw<<<97, 256, 0, stream>>>(W1, W2, W3, wt, tbuf, gcur, scur);
  k_bucket<<<NBLK_B, 256, 0, stream>>>(ei, bpk, gcur);
  k_sub<<<NGRP * NSLOT, 256, 0, stream>>>(bpk, gcur, ssub, scur);
  k_cntd<<<NSUB, 256, 0, stream>>>(ssub, scur, dinv, wsum);
  k_scan2<<<1, 512, 0, stream>>>(wsum, wbase, offs);
  k_csr<<<NSUB, 256, 0, stream>>>(ssub, scur, wbase, offs, csr);

  const int gb = (NN + 63) / 64;
  const int ab = (NN + 3) / 4;
  k_gemm<true><<<gb, 256, 0, stream>>>(x, wt, dinv, tbuf);
  k_agg<true><<<ab, 256, 0, stream>>>(tbuf, offs, csr, dinv, b1, hbuf);
  k_gemm<false><<<gb, 256, 0, stream>>>(hbuf, wt + 8192, dinv, tbuf);
  k_agg<true><<<ab, 256, 0, stream>>>(tbuf, offs, csr, dinv, b2, hbuf);
  k_gemm<false><<<gb, 256, 0, stream>>>(hbuf, wt + 16384, dinv, tbuf);
  k_agg<false><<<ab, 256, 0, stream>>>(tbuf, offs, csr, dinv, b3, out);
}